// Round 25
// baseline (966.604 us; speedup 1.0000x reference)
//
#include <hip/hip_runtime.h>
#include <hip/hip_bf16.h>
#include <math.h>

typedef __hip_bfloat16 bf16;
typedef unsigned int u32;
typedef unsigned long long u64;
using short8 = __attribute__((ext_vector_type(8))) short;
using f32x4  = __attribute__((ext_vector_type(4))) float;

__device__ __forceinline__ float b2f(bf16 v){ return __bfloat162float(v); }
__device__ __forceinline__ bf16  f2b(float v){ return __float2bfloat16(v); }
__device__ __forceinline__ float plo(u32 u){ return __uint_as_float(u << 16); }
__device__ __forceinline__ float phi(u32 u){ return __uint_as_float(u & 0xffff0000u); }

__device__ __forceinline__ void gld16(const void* g, void* l)
{
  __builtin_amdgcn_global_load_lds(
      (const __attribute__((address_space(1))) u32*)g,
      (__attribute__((address_space(3))) u32*)l, 16, 0, 0);
}

// ---- dtype probe ----
__global__ void k_detect(const u32* probe, int* flag)
{
  if (threadIdx.x == 0 && blockIdx.x == 0)
    *flag = (*probe == 0x3F800000u) ? 0 : 1;
}

// ---- all param arrays -> canonical bf16, one dispatch ----
struct PPack { const void* s[25]; u32 off[26]; };
__global__ __launch_bounds__(256) void k_convall(PPack pp, bf16* P, const int* flag)
{
  const u32 i = blockIdx.x * 256 + threadIdx.x;
  if (i >= pp.off[25]) return;
  int lo = 0, hi = 25;
  while (hi - lo > 1) { const int mid = (lo + hi) >> 1; if (i >= pp.off[mid]) lo = mid; else hi = mid; }
  const u32 j = i - pp.off[lo];
  P[i] = *flag ? ((const bf16*)pp.s[lo])[j] : f2b(((const float*)pp.s[lo])[j]);
}

// ---- zero only the 1-pixel border ring of a padded channels-last buffer ----
__global__ __launch_bounds__(256) void k_zborder(bf16* buf, int Hp, int C, int nimg)
{
  const int per = 4 * Hp - 4;
  const int c8 = C >> 3;
  const int total = nimg * per * c8;
  const int i = blockIdx.x * 256 + threadIdx.x;
  if (i >= total) return;
  const int ch8 = i % c8;
  const int pb = i / c8;
  const int img = pb / per;
  const int b = pb - img * per;
  int y, x;
  if (b < Hp) { y = 0; x = b; }
  else if (b < 2 * Hp) { y = Hp - 1; x = b - Hp; }
  else {
    const int r = b - 2 * Hp;
    const int side = r / (Hp - 2);
    y = 1 + r - side * (Hp - 2);
    x = side ? (Hp - 1) : 0;
  }
  uint4 z = {0, 0, 0, 0};
  *reinterpret_cast<uint4*>(buf + (((size_t)img * Hp + y) * Hp + x) * C + ch8 * 8) = z;
}

// ---- vectorized im2col: x (f32 or bf16) -> A_im bf16 (8192 x 3072) ----
__global__ __launch_bounds__(128) void k_im2col(const void* x, bf16* A, const int* flag)
{
  const int m = blockIdx.y;
  const int k8 = blockIdx.x * 128 + threadIdx.x;
  const int k = k8 * 8;
  const int b = m >> 8, n = m & 255;
  const int gy = n >> 4, gx = n & 15;
  const int c = k >> 10, r = (k >> 5) & 31, pp = k & 31;
  const size_t src = (((size_t)(b * 3 + c) * 512) + gy * 32 + r) * 512 + gx * 32 + pp;
  bf16 ov[8];
  if (*flag) {
    const bf16* xp = (const bf16*)x + src;
    #pragma unroll
    for (int i = 0; i < 8; ++i) ov[i] = xp[i];
  } else {
    const float4 v0 = *reinterpret_cast<const float4*>((const float*)x + src);
    const float4 v1 = *reinterpret_cast<const float4*>((const float*)x + src + 4);
    ov[0]=f2b(v0.x); ov[1]=f2b(v0.y); ov[2]=f2b(v0.z); ov[3]=f2b(v0.w);
    ov[4]=f2b(v1.x); ov[5]=f2b(v1.y); ov[6]=f2b(v1.z); ov[7]=f2b(v1.w);
  }
  *reinterpret_cast<uint4*>(A + (size_t)m * 3072 + k) = *reinterpret_cast<const uint4*>(ov);
}

// === MFMA GEMM, BM=FM*32, BN in {128,256}; optional dbuf; split-K via grid.z ===
template<int EPI, int FM, int BN, bool DB>
__global__ __launch_bounds__(256, 2) void gemm_t(
    const bf16* __restrict__ A, const bf16* __restrict__ Bw,
    const bf16* __restrict__ bias, const bf16* res, bf16* C,
    const float* __restrict__ cnorm, u64* __restrict__ ku,
    int M, int N, int K, int Kc)
{
  constexpr int BM = FM * 32;
  constexpr int FN = BN / 32;
  __shared__ alignas(16) bf16 As[DB ? 2 : 1][BM * 64];
  __shared__ alignas(16) bf16 Bs[DB ? 2 : 1][BN * 64];
  const int tid = threadIdx.x;
  const int bn = blockIdx.x * BN, bm = blockIdx.y * BM;
  const int z = blockIdx.z;
  const int kb = z * Kc;
  const int l = tid & 63, w = tid >> 6;
  const int wm = w >> 1, wn = w & 1;
  const int lg = l >> 4, lr = l & 15;
  const int sr8 = l >> 3;
  const int sch = (l & 7) ^ sr8;
  f32x4 acc[FM][FN];
  #pragma unroll
  for (int fm = 0; fm < FM; ++fm)
    #pragma unroll
    for (int fn = 0; fn < FN; ++fn) acc[fm][fn] = (f32x4){0.f, 0.f, 0.f, 0.f};

  auto stage = [&](int bb, int k0) {
    char* ab = (char*)As[bb];
    char* bp = (char*)Bs[bb];
    #pragma unroll
    for (int it = 0; it < FM; ++it) {
      const int r = w * 8 + it * 32 + sr8;
      gld16(A + (size_t)(bm + r) * K + k0 + sch * 8, ab + w * 1024 + it * 4096);
    }
    #pragma unroll
    for (int it = 0; it < BN / 32; ++it) {
      const int r = w * 8 + it * 32 + sr8;
      gld16(Bw + (size_t)(bn + r) * K + k0 + sch * 8, bp + w * 1024 + it * 4096);
    }
  };
  auto compute = [&](int bb) {
    const char* ab = (const char*)As[bb];
    const char* bp = (const char*)Bs[bb];
    #pragma unroll
    for (int ks = 0; ks < 2; ++ks) {
      short8 af[FM], bfr[FN];
      #pragma unroll
      for (int fm = 0; fm < FM; ++fm) {
        const int r = wm * (FM * 16) + fm * 16 + lr;
        af[fm] = *reinterpret_cast<const short8*>(ab + r * 128 + (((lg + ks * 4) ^ (r & 7)) * 16));
      }
      #pragma unroll
      for (int fn = 0; fn < FN; ++fn) {
        const int r = wn * (BN / 2) + fn * 16 + lr;
        bfr[fn] = *reinterpret_cast<const short8*>(bp + r * 128 + (((lg + ks * 4) ^ (r & 7)) * 16));
      }
      #pragma unroll
      for (int fm = 0; fm < FM; ++fm)
        #pragma unroll
        for (int fn = 0; fn < FN; ++fn)
          acc[fm][fn] = __builtin_amdgcn_mfma_f32_16x16x32_bf16(af[fm], bfr[fn], acc[fm][fn], 0, 0, 0);
    }
  };

  const int nt = Kc >> 6;
  if (DB) {
    stage(0, kb);
    __syncthreads();
    for (int t = 0; t < nt; ++t) {
      const int cur = t & 1;
      if (t + 1 < nt) stage(cur ^ 1, kb + ((t + 1) << 6));
      compute(cur);
      __syncthreads();
    }
  } else {
    for (int t = 0; t < nt; ++t) {
      if (t) __syncthreads();
      stage(0, kb + (t << 6));
      __syncthreads();
      compute(0);
    }
  }

  if (EPI == 3) {
    __shared__ u64 skey[BM][2];
    float cn[FN];
    #pragma unroll
    for (int fn = 0; fn < FN; ++fn) cn[fn] = cnorm[bn + wn * (BN / 2) + fn * 16 + lr];
    #pragma unroll
    for (int fm = 0; fm < FM; ++fm) {
      #pragma unroll
      for (int r = 0; r < 4; ++r) {
        u64 best = ~0ull;
        #pragma unroll
        for (int fn = 0; fn < FN; ++fn) {
          const int col = bn + wn * (BN / 2) + fn * 16 + lr;
          const float d = cn[fn] - 2.0f * acc[fm][fn][r];
          u32 u = __float_as_uint(d);
          u = (u & 0x80000000u) ? ~u : (u | 0x80000000u);
          const u64 key = ((u64)u << 32) | (u32)col;
          best = key < best ? key : best;
        }
        #pragma unroll
        for (int mk = 1; mk < 16; mk <<= 1) {
          const u64 o = __shfl_xor(best, mk, 64);
          best = o < best ? o : best;
        }
        if (lr == 0) skey[wm * (FM * 16) + fm * 16 + lg * 4 + r][wn] = best;
      }
    }
    __syncthreads();
    if (tid < BM) {
      const u64 a = skey[tid][0], b = skey[tid][1];
      ku[(size_t)blockIdx.x * M + bm + tid] = a < b ? a : b;
    }
  } else if (EPI == 4) {
    #pragma unroll
    for (int fm = 0; fm < FM; ++fm) {
      const int m0 = bm + wm * (FM * 16) + fm * 16 + lg * 4;
      #pragma unroll
      for (int fn = 0; fn < FN; ++fn) {
        const int n = bn + wn * (BN / 2) + fn * 16 + lr;
        #pragma unroll
        for (int r = 0; r < 4; ++r)
          C[((size_t)z * M + m0 + r) * N + n] = f2b(acc[fm][fn][r]);
      }
    }
  } else {
    #pragma unroll
    for (int fm = 0; fm < FM; ++fm) {
      const int m0 = bm + wm * (FM * 16) + fm * 16 + lg * 4;
      #pragma unroll
      for (int fn = 0; fn < FN; ++fn) {
        const int n = bn + wn * (BN / 2) + fn * 16 + lr;
        const float bs = b2f(bias[n]);
        #pragma unroll
        for (int r = 0; r < 4; ++r) {
          float v = acc[fm][fn][r] + bs;
          if (EPI == 1) v = 0.5f * v * (1.0f + erff(v * 0.70710678118654752f));
          if (EPI == 2) v += b2f(res[(size_t)(m0 + r) * N + n]);
          C[(size_t)(m0 + r) * N + n] = f2b(v);
        }
      }
    }
  }
}

// ====== fused per-bt transformer phase 1: qkv -> attention -> attnout+res+LN1 ======
__global__ __launch_bounds__(256, 1) void k_fat1(
    bf16* __restrict__ hbuf,
    const bf16* __restrict__ Wqkv, const bf16* __restrict__ Bqkv,
    const bf16* __restrict__ Wo, const bf16* __restrict__ Bo,
    const bf16* __restrict__ lw, const bf16* __restrict__ lb)
{
  __shared__ alignas(16) bf16 hs[32 * 256];
  __shared__ alignas(16) bf16 ao[32 * 256];
  __shared__ alignas(16) bf16 astage[128 * 64];
  __shared__ bf16 att[3 * 9216];
  __shared__ float ps[32][33];
  __shared__ float rs[32];
  __shared__ float psum[32][4], psq[32][4];
  __shared__ float mstat[32], istat[32];

  const int bt = blockIdx.x;
  const int tid = threadIdx.x;
  const int l = tid & 63, w = tid >> 6;
  const int lg = l >> 4, lr = l & 15;
  const int sr8 = l >> 3;
  const int sch = (l & 7) ^ sr8;
  char* hsb = (char*)hs;
  char* aob = (char*)ao;
  char* asb = (char*)astage;

  #pragma unroll
  for (int call = 0; call < 4; ++call) {
    const int id = call * 256 + tid;
    const int s = id >> 5, within = id & 31;
    const int grp = within >> 3, c = within & 7;
    gld16(hbuf + (size_t)(s * 256 + bt) * 256 + grp * 64 + ((c ^ (s & 7)) * 8),
          hsb + call * 4096 + w * 1024);
  }

  for (int at = 0; at < 6; ++at) {
    f32x4 acc[2][2];
    #pragma unroll
    for (int fm = 0; fm < 2; ++fm)
      #pragma unroll
      for (int fn = 0; fn < 2; ++fn) acc[fm][fn] = (f32x4){0.f, 0.f, 0.f, 0.f};
    for (int kst = 0; kst < 4; ++kst) {
      __syncthreads();
      #pragma unroll
      for (int it = 0; it < 4; ++it) {
        const int r = w * 8 + it * 32 + sr8;
        gld16(Wqkv + (size_t)(at * 128 + r) * 256 + kst * 64 + sch * 8,
              asb + w * 1024 + it * 4096);
      }
      __syncthreads();
      #pragma unroll
      for (int ks = 0; ks < 2; ++ks) {
        short8 af[2], bfr[2];
        #pragma unroll
        for (int fm = 0; fm < 2; ++fm) {
          const int r = w * 32 + fm * 16 + lr;
          af[fm] = *reinterpret_cast<const short8*>(asb + r * 128 + (((lg + ks * 4) ^ (r & 7)) * 16));
        }
        #pragma unroll
        for (int fn = 0; fn < 2; ++fn) {
          const int sr = fn * 16 + lr;
          bfr[fn] = *reinterpret_cast<const short8*>(hsb + sr * 512 + kst * 128 + (((lg + ks * 4) ^ (sr & 7)) * 16));
        }
        #pragma unroll
        for (int fm = 0; fm < 2; ++fm)
          #pragma unroll
          for (int fn = 0; fn < 2; ++fn)
            acc[fm][fn] = __builtin_amdgcn_mfma_f32_16x16x32_bf16(af[fm], bfr[fn], acc[fm][fn], 0, 0, 0);
      }
    }
    #pragma unroll
    for (int fm = 0; fm < 2; ++fm) {
      #pragma unroll
      for (int fn = 0; fn < 2; ++fn) {
        const int s = fn * 16 + lr;
        #pragma unroll
        for (int r = 0; r < 4; ++r) {
          const int n = at * 128 + w * 32 + fm * 16 + lg * 4 + r;
          const int p = n >> 8, rem = n & 255;
          att[p * 9216 + (rem >> 5) * 1152 + s * 36 + (rem & 31)] =
              f2b(acc[fm][fn][r] + b2f(Bqkv[n]));
        }
      }
    }
  }
  __syncthreads();

  const int s_a = tid >> 3, j_a = tid & 7;
  for (int hd = 0; hd < 8; ++hd) {
    const bf16* qrow = att + hd * 1152 + s_a * 36;
    float sc[4];
    #pragma unroll
    for (int e = 0; e < 4; ++e) {
      const int t = j_a + 8 * e;
      const bf16* krow = att + 9216 + hd * 1152 + t * 36;
      float v = 0.f;
      #pragma unroll
      for (int dd = 0; dd < 32; ++dd) v += b2f(qrow[dd]) * b2f(krow[dd]);
      sc[e] = v * 0.17677669529663687f;
    }
    float mx = fmaxf(fmaxf(sc[0], sc[1]), fmaxf(sc[2], sc[3]));
    #pragma unroll
    for (int mk = 1; mk < 8; mk <<= 1) mx = fmaxf(mx, __shfl_xor(mx, mk, 64));
    float sm = 0.f; float ex[4];
    #pragma unroll
    for (int e = 0; e < 4; ++e) { ex[e] = expf(sc[e] - mx); sm += ex[e]; }
    #pragma unroll
    for (int mk = 1; mk < 8; mk <<= 1) sm += __shfl_xor(sm, mk, 64);
    #pragma unroll
    for (int e = 0; e < 4; ++e) ps[s_a][j_a + 8 * e] = ex[e];
    if (j_a == 0) rs[s_a] = 1.0f / sm;
    __syncthreads();
    const float rinv = rs[s_a];
    float av[4];
    #pragma unroll
    for (int e = 0; e < 4; ++e) {
      const int dd = j_a * 4 + e;
      float a = 0.f;
      #pragma unroll
      for (int t = 0; t < 32; ++t)
        a += ps[s_a][t] * b2f(att[2 * 9216 + hd * 1152 + t * 36 + dd]);
      av[e] = a * rinv;
    }
    alignas(8) bf16 ov[4];
    #pragma unroll
    for (int e = 0; e < 4; ++e) ov[e] = f2b(av[e]);
    const int clog = (hd & 1) * 4 + (j_a >> 1);
    *reinterpret_cast<ushort4*>(aob + s_a * 512 + (hd >> 1) * 128 +
        ((clog ^ (s_a & 7)) * 16) + (j_a & 1) * 8) =
        *reinterpret_cast<const ushort4*>(ov);
    __syncthreads();
  }

  float vals[2][2][2][4];
  for (int at = 0; at < 2; ++at) {
    f32x4 acc[2][2];
    #pragma unroll
    for (int fm = 0; fm < 2; ++fm)
      #pragma unroll
      for (int fn = 0; fn < 2; ++fn) acc[fm][fn] = (f32x4){0.f, 0.f, 0.f, 0.f};
    for (int kst = 0; kst < 4; ++kst) {
      __syncthreads();
      #pragma unroll
      for (int it = 0; it < 4; ++it) {
        const int r = w * 8 + it * 32 + sr8;
        gld16(Wo + (size_t)(at * 128 + r) * 256 + kst * 64 + sch * 8,
              asb + w * 1024 + it * 4096);
      }
      __syncthreads();
      #pragma unroll
      for (int ks = 0; ks < 2; ++ks) {
        short8 af[2], bfr[2];
        #pragma unroll
        for (int fm = 0; fm < 2; ++fm) {
          const int r = w * 32 + fm * 16 + lr;
          af[fm] = *reinterpret_cast<const short8*>(asb + r * 128 + (((lg + ks * 4) ^ (r & 7)) * 16));
        }
        #pragma unroll
        for (int fn = 0; fn < 2; ++fn) {
          const int sr = fn * 16 + lr;
          bfr[fn] = *reinterpret_cast<const short8*>(aob + sr * 512 + kst * 128 + (((lg + ks * 4) ^ (sr & 7)) * 16));
        }
        #pragma unroll
        for (int fm = 0; fm < 2; ++fm)
          #pragma unroll
          for (int fn = 0; fn < 2; ++fn)
            acc[fm][fn] = __builtin_amdgcn_mfma_f32_16x16x32_bf16(af[fm], bfr[fn], acc[fm][fn], 0, 0, 0);
      }
    }
    #pragma unroll
    for (int fm = 0; fm < 2; ++fm)
      #pragma unroll
      for (int fn = 0; fn < 2; ++fn)
        #pragma unroll
        for (int r = 0; r < 4; ++r) vals[at][fm][fn][r] = acc[fm][fn][r];
  }

  float s1[2] = {0.f, 0.f}, s2[2] = {0.f, 0.f};
  #pragma unroll
  for (int at = 0; at < 2; ++at) {
    #pragma unroll
    for (int fm = 0; fm < 2; ++fm) {
      const int n4 = at * 128 + w * 32 + fm * 16 + lg * 4;
      #pragma unroll
      for (int fn = 0; fn < 2; ++fn) {
        const int s = fn * 16 + lr;
        const ushort4 hr = *reinterpret_cast<const ushort4*>(
            hsb + s * 512 + (n4 >> 6) * 128 + ((((n4 >> 3) & 7) ^ (s & 7)) * 16) + (n4 & 7) * 2);
        const bf16* hb = reinterpret_cast<const bf16*>(&hr);
        #pragma unroll
        for (int r = 0; r < 4; ++r) {
          const float v = vals[at][fm][fn][r] + b2f(Bo[n4 + r]) + b2f(hb[r]);
          vals[at][fm][fn][r] = v;
          s1[fn] += v;
          s2[fn] += v * v;
        }
      }
    }
  }
  #pragma unroll
  for (int fn = 0; fn < 2; ++fn) {
    float a = s1[fn], b = s2[fn];
    a += __shfl_xor(a, 16, 64); a += __shfl_xor(a, 32, 64);
    b += __shfl_xor(b, 16, 64); b += __shfl_xor(b, 32, 64);
    if (lg == 0) { psum[fn * 16 + lr][w] = a; psq[fn * 16 + lr][w] = b; }
  }
  __syncthreads();
  if (tid < 32) {
    float sa = 0.f, sb = 0.f;
    #pragma unroll
    for (int k = 0; k < 4; ++k) { sa += psum[tid][k]; sb += psq[tid][k]; }
    const float m = sa * (1.0f / 256.0f);
    mstat[tid] = m;
    istat[tid] = 1.0f / sqrtf(sb * (1.0f / 256.0f) - m * m + 1e-5f);
  }
  __syncthreads();
  #pragma unroll
  for (int at = 0; at < 2; ++at) {
    #pragma unroll
    for (int fm = 0; fm < 2; ++fm) {
      const int n4 = at * 128 + w * 32 + fm * 16 + lg * 4;
      #pragma unroll
      for (int fn = 0; fn < 2; ++fn) {
        const int s = fn * 16 + lr;
        const float m = mstat[s], inv = istat[s];
        alignas(8) bf16 ov[4];
        #pragma unroll
        for (int r = 0; r < 4; ++r)
          ov[r] = f2b((vals[at][fm][fn][r] - m) * inv * b2f(lw[n4 + r]) + b2f(lb[n4 + r]));
        *reinterpret_cast<ushort4*>(hbuf + (size_t)(s * 256 + bt) * 256 + n4) =
            *reinterpret_cast<const ushort4*>(ov);
      }
    }
  }
}

// ---- split-K reduce (bf16 partials) + bias (+res) + LN (+optional 2nd LN) ----
template<bool DOLN>
__global__ __launch_bounds__(256) void k_lnred(
    const bf16* __restrict__ Pf, const bf16* __restrict__ bias,
    const bf16* res, const bf16* __restrict__ lw, const bf16* __restrict__ lb,
    const bf16* lw2, const bf16* lb2,
    bf16* h, int kc)
{
  __shared__ float red[256];
  __shared__ float stat[2];
  const int row = blockIdx.x, d = threadIdx.x;
  float s = 0.f;
  for (int z = 0; z < kc; ++z) s += b2f(Pf[((size_t)z * 8192 + row) * 256 + d]);
  s += b2f(bias[d]);
  if (res) s += b2f(res[(size_t)row * 256 + d]);
  if (!DOLN) { h[(size_t)row * 256 + d] = f2b(s); return; }
  red[d] = s;
  __syncthreads();
  for (int off = 128; off > 0; off >>= 1) {
    if (d < off) red[d] += red[d + off];
    __syncthreads();
  }
  if (d == 0) stat[0] = red[0] * (1.0f / 256.0f);
  __syncthreads();
  float m = stat[0];
  red[d] = (s - m) * (s - m);
  __syncthreads();
  for (int off = 128; off > 0; off >>= 1) {
    if (d < off) red[d] += red[d + off];
    __syncthreads();
  }
  if (d == 0) stat[1] = 1.0f / sqrtf(red[0] * (1.0f / 256.0f) + 1e-5f);
  __syncthreads();
  float y = (s - m) * stat[1] * b2f(lw[d]) + b2f(lb[d]);
  if (lw2) {
    __syncthreads();
    red[d] = y;
    __syncthreads();
    for (int off = 128; off > 0; off >>= 1) {
      if (d < off) red[d] += red[d + off];
      __syncthreads();
    }
    if (d == 0) stat[0] = red[0] * (1.0f / 256.0f);
    __syncthreads();
    m = stat[0];
    red[d] = (y - m) * (y - m);
    __syncthreads();
    for (int off = 128; off > 0; off >>= 1) {
      if (d < off) red[d] += red[d + off];
      __syncthreads();
    }
    if (d == 0) stat[1] = 1.0f / sqrtf(red[0] * (1.0f / 256.0f) + 1e-5f);
    __syncthreads();
    y = (y - m) * stat[1] * b2f(lw2[d]) + b2f(lb2[d]);
  }
  h[(size_t)row * 256 + d] = f2b(y);
}

// ---- VQ merge over u64 keys (deterministic) ----
__global__ __launch_bounds__(256) void k_vqmerge(
    const u64* __restrict__ ku, int* __restrict__ idx, int M, int NB)
{
  const int r = blockIdx.x * 256 + threadIdx.x;
  if (r >= M) return;
  u64 best = ku[r];
  for (int nb = 1; nb < NB; ++nb) {
    const u64 k = ku[(size_t)nb * M + r];
    best = k < best ? k : best;
  }
  idx[r] = (int)(best & 0xFFFFFFFFull);
}

// ---- codebook norms ----
__global__ __launch_bounds__(256) void k_cnorm(const bf16* __restrict__ cb, float* __restrict__ cn)
{
  const int j = blockIdx.x * 256 + threadIdx.x;
  const u32* p = (const u32*)(cb + (size_t)j * 256);
  float s = 0.f;
  for (int k = 0; k < 128; ++k) {
    const u32 v = p[k];
    const float a = plo(v), b = phi(v);
    s += a * a + b * b;
  }
  cn[j] = s;
}

// ---- gather codebook -> padded channels-last a0 + per-row loss partials ----
__global__ __launch_bounds__(256) void k_gather(
    const bf16* h, const bf16* cb, const int* idx, bf16* a0, float* lsum)
{
  __shared__ float red[256];
  const int row = blockIdx.x, d = threadIdx.x;
  const int code = idx[row] & 8191;
  const float q = b2f(cb[(size_t)code * 256 + d]);
  const float x = b2f(h[(size_t)row * 256 + d]);
  red[d] = (q - x) * (q - x);
  __syncthreads();
  for (int off = 128; off > 0; off >>= 1) {
    if (d < off) red[d] += red[d + off];
    __syncthreads();
  }
  if (d == 0) lsum[row] = red[0];
  const int b = row >> 8, n = row & 255;
  const int y = n >> 4, xc = n & 15;
  a0[(((size_t)b * 18 + y + 1) * 18 + (xc + 1)) * 256 + d] = f2b(q);
}

// ---- deterministic loss reduce -> f32 scalar ----
__global__ __launch_bounds__(256) void k_loss(const float* lsum, float* out)
{
  __shared__ float red[256];
  const int tid = threadIdx.x;
  float v = 0.f;
  for (int i = 0; i < 32; ++i) v += lsum[tid + 256 * i];
  red[tid] = v;
  __syncthreads();
  for (int off = 128; off > 0; off >>= 1) {
    if (tid < off) red[tid] += red[tid + off];
    __syncthreads();
  }
  if (tid == 0)
    out[0] = red[0] * (1.25f / 2097152.0f);
}

// ---- decoder weight transform ----
__global__ __launch_bounds__(256) void k_wtrans(
    const bf16* __restrict__ w, bf16* __restrict__ wt,
    int Cin, int lCin, int CoutR, int CoutP)
{
  const int K = Cin << 2;
  const int total = 4 * CoutP * K;
  const int i = blockIdx.x * 256 + threadIdx.x;
  if (i >= total) return;
  const int p = i / (CoutP * K);
  const int rem = i - p * (CoutP * K);
  const int co = rem / K;
  const int k = rem - co * K;
  const int tap = k >> lCin, ci = k - (tap << lCin);
  const int py = p >> 1, px = p & 1, ty = tap >> 1, tx = tap & 1;
  bf16 v = f2b(0.f);
  if (co < CoutR)
    v = w[(((size_t)ci * CoutR + co) * 4 + py + 2 * ty) * 4 + px + 2 * tx];
  wt[i] = v;
}

// ====== decoder convT implicit MFMA GEMM, double-buffered 2-phase ======
__global__ __launch_bounds__(256, 2) void convt64(
    const bf16* __restrict__ in, const bf16* __restrict__ Wt,
    const bf16* __restrict__ bias, bf16* __restrict__ outp,
    int H, int lH, int Cin, int lCin, int Cout)
{
  __shared__ alignas(16) bf16 As[2][128 * 64];
  __shared__ alignas(16) bf16 Bs[2][64 * 64];
  const int tid = threadIdx.x;
  const int pz = blockIdx.z;
  const int py = pz >> 1, px = pz & 1;
  const int K = Cin << 2;
  const int bn = blockIdx.x * 64, bm = blockIdx.y * 128;
  const bf16* Bw = Wt + (size_t)pz * Cout * K;
  const int l = tid & 63, w = tid >> 6;
  const int wm = w >> 1, wn = w & 1;
  const int lg = l >> 4, lr = l & 15;
  const int sr8 = l >> 3;
  const int sch = (l & 7) ^ sr8;
  const int Hp = H + 2;
  f32x4 acc[4][2];
  #pragma unroll
  for (int fm = 0; fm < 4; ++fm)
    #pragma unroll
    for (int fn = 0; fn < 2; ++fn) acc[fm][fn] = (f32x4){0.f, 0.f, 0.f, 0.f};

  size_t pixbase[4];
  #pragma unroll
  for (int it = 0; it < 4; ++it) {
    const int m = bm + w * 8 + it * 32 + sr8;
    const int b = m >> (2 * lH);
    const int rem = m & ((1 << (2 * lH)) - 1);
    const int jj = rem >> lH, ii = rem & (H - 1);
    pixbase[it] = ((size_t)(b * Hp + jj) * Hp + ii);
  }

  auto stage = [&](int bb, int k0) {
    char* ab = (char*)As[bb];
    char* bp = (char*)Bs[bb];
    const int tap = k0 >> lCin;
    const int ty = tap >> 1, tx = tap & 1;
    const int sy = (1 - py) + (1 - ty);
    const int sx = (1 - px) + (1 - tx);
    const int ci0 = (k0 - (tap << lCin)) + sch * 8;
    #pragma unroll
    for (int it = 0; it < 4; ++it)
      gld16(in + (pixbase[it] + (size_t)sy * Hp + sx) * Cin + ci0,
            ab + w * 1024 + it * 4096);
    #pragma unroll
    for (int it = 0; it < 2; ++it) {
      const int r = w * 8 + it * 32 + sr8;
      gld16(Bw + (size_t)(bn + r) * K + k0 + sch * 8, bp + w * 1024 + it * 4096);
    }
  };

  const int nt = K >> 6;
  stage(0, 0);
  __syncthreads();
  for (int t = 0; t < nt; ++t) {
    const int cur = t & 1;
    if (t + 1 < nt) stage(cur ^ 1, (t + 1) << 6);
    const char* ab = (const char*)As[cur];
    const char* bb = (const char*)Bs[cur];
    #pragma unroll
    for (int ks = 0; ks < 2; ++ks) {
      short8 af[4], bfr[2];
      #pragma unroll
      for (int fm = 0; fm < 4; ++fm) {
        const int r = wm * 64 + fm * 16 + lr;
        af[fm] = *reinterpret_cast<const short8*>(ab + r * 128 + (((lg + ks * 4) ^ (r & 7)) * 16));
      }
      #pragma unroll
      for (int fn = 0; fn < 2; ++fn) {
        const int r = wn * 32 + fn * 16 + lr;
        bfr[fn] = *reinterpret_cast<const short8*>(bb + r * 128 + (((lg + ks * 4) ^ (r & 7)) * 16));
      }
      #pragma unroll
      for (int fm = 0; fm < 4; ++fm)
        #pragma unroll
        for (int fn = 0; fn < 2; ++fn)
          acc[fm][fn] = __builtin_amdgcn_mfma_f32_16x16x32_bf16(af[fm], bfr[fn], acc[fm][fn], 0, 0, 0);
    }
    __syncthreads();
  }

  const int Ho = 2 * H, Hop = Ho + 2;
  #pragma unroll
  for (int fm = 0; fm < 4; ++fm) {
    const int m0 = bm + wm * 64 + fm * 16 + lg * 4;
    #pragma unroll
    for (int fn = 0; fn < 2; ++fn) {
      const int n = bn + wn * 32 + fn * 16 + lr;
      #pragma unroll
      for (int r = 0; r < 4; ++r) {
        const int m = m0 + r;
        const int b = m >> (2 * lH);
        const int rem = m & ((1 << (2 * lH)) - 1);
        const int jj = rem >> lH, ii = rem & (H - 1);
        const int oy = 2 * jj + (1 - py), ox = 2 * ii + (1 - px);
        const float v = fmaxf(acc[fm][fn][r] + b2f(bias[n]), 0.f);
        outp[((size_t)(b * Hop + oy + 1) * Hop + ox + 1) * Cout + n] = f2b(v);
      }
    }
  }
}

// ---- final decoder layer (Cout=3): coalesced vector kernel ----
__global__ __launch_bounds__(256) void k_dec3(
    const bf16* __restrict__ a3, const bf16* __restrict__ wt3,
    const bf16* __restrict__ bias, float* __restrict__ xhat, int chunkBase)
{
  __shared__ float wl[3][264];
  const int tid = threadIdx.x;
  const int pz = blockIdx.y;
  const int py = pz >> 1, px = pz & 1;
  for (int i = tid; i < 768; i += 256) {
    const int co = i >> 8, k = i & 255;
    wl[co][k] = b2f(wt3[(pz * 3 + co) * 256 + k]);
  }
  __syncthreads();
  const int b = blockIdx.z;
  const int p = blockIdx.x * 64 + (tid >> 2);
  const int jj = p >> 7, ii = p & 127;
  const int ch4 = tid & 3;
  float a0 = 0.f, a1 = 0.f, a2 = 0.f;
  #pragma unroll
  for (int ty = 0; ty < 2; ++ty) {
    #pragma unroll
    for (int tx = 0; tx < 2; ++tx) {
      const int sy = (1 - py) + (1 - ty), sx = (1 - px) + (1 - tx);
      const int tap = ty * 2 + tx;
      const u32* ip = (const u32*)(a3 + ((size_t)(b * 130 + jj + sy) * 130 + ii + sx) * 64) + ch4 * 8;
      const float* w0 = &wl[0][tap * 64 + ch4 * 16];
      const float* w1 = &wl[1][tap * 64 + ch4 * 16];
      const float* w2 = &wl[2][tap * 64 + ch4 * 16];
      #pragma unroll
      for (int kk = 0; kk < 8; ++kk) {
        const u32 v = ip[kk];
        const float e0 = plo(v), e1 = phi(v);
        a0 += e0 * w0[2 * kk] + e1 * w0[2 * kk + 1];
        a1 += e0 * w1[2 * kk] + e1 * w1[2 * kk + 1];
        a2 += e0 * w2[2 * kk] + e1 * w2[2 * kk + 1];
      }
    }
  }
  a0 += __shfl_xor(a0, 1, 64); a0 += __shfl_xor(a0, 2, 64);
  a1 += __shfl_xor(a1, 1, 64); a1 += __shfl_xor(a1, 2, 64);
  a2 += __shfl_xor(a2, 1, 64); a2 += __shfl_xor(a2, 2, 64);
  if (ch4 < 3) {
    const float av = ch4 == 0 ? a0 : (ch4 == 1 ? a1 : a2);
    const int oy = 2 * jj + (1 - py), ox = 2 * ii + (1 - px);
    const float t = av + b2f(bias[ch4]);
    xhat[(((size_t)(chunkBase + b) * 3 + ch4) * 256 + oy) * 256 + ox] =
        1.0f / (1.0f + expf(-t));
  }
}

// =====================================================================
extern "C" void kernel_launch(void* const* d_in, const int* in_sizes, int n_in,
                              void* d_out, int out_size, void* d_ws, size_t ws_size,
                              hipStream_t stream)
{
  float* xhat = (float*)d_out;
  float* lossout = xhat + (out_size - 1);

  const size_t NEED = 130195456;
  if (ws_size < NEED) return;

  char* ws = (char*)d_ws;
  int*   flag  = (int*)  (ws + 0);
  float* lsum  = (float*)(ws + 1024);
  int*   idx   = (int*)  (ws + 65536);
  u64*   ku    = (u64*)  (ws + 131072);
  bf16*  P     = (bf16*) (ws + 8519680);
  bf16*  WT    = (bf16*) (ws + 27262976);
  float* cnorm = (float*)(ws + 30900224);
  bf16*  hbuf  = (bf16*) (ws + 31457280);
  bf16*  A_im  = (bf16*) (ws + 35651584);
  bf16*  ffb   = (bf16*) (ws + 52428800);
  bf16*  Pfb   = (bf16*) (ws + 85983232);
  bf16*  a0    = (bf16*) (ws + 35651584);
  bf16*  a1    = (bf16*) (ws + 40960000);
  bf16*  a2    = (bf16*) (ws + 59899904);
  bf16*  a3    = (bf16*) (ws + 95584256);

  k_detect<<<1, 64, 0, stream>>>((const u32*)d_in[7], flag);

  size_t poff[26]; poff[1] = 0;
  for (int i = 2; i <= 25; ++i) poff[i] = poff[i - 1] + (size_t)in_sizes[i - 1];
  const size_t ptotal = poff[25] + (size_t)in_sizes[25];
  PPack pp;
  for (int i = 0; i < 25; ++i) { pp.s[i] = d_in[i + 1]; pp.off[i] = (u32)poff[i + 1]; }
  pp.off[25] = (u32)ptotal;
  k_convall<<<(int)((ptotal + 255) / 256), 256, 0, stream>>>(pp, P, flag);

  const bf16 *patch_w = P + poff[1],  *patch_b = P + poff[2];
  const bf16 *qkv_w   = P + poff[3],  *qkv_b   = P + poff[4];
  const bf16 *out_w   = P + poff[5],  *out_b   = P + poff[6];
  const bf16 *ln1_w   = P + poff[7],  *ln1_b   = P + poff[8];
  const bf16 *ln2_w   = P + poff[9],  *ln2_b   = P + poff[10];
  const bf16 *ff1_w   = P + poff[11], *ff1_b   = P + poff[12];
  const bf16 *ff2_w   = P + poff[13], *ff2_b   = P + poff[14];
  const bf16 *lnf_w   = P + poff[15], *lnf_b   = P + poff[16];
  const bf16 *codebook= P + poff[17];
  const bf16 *dec_w0  = P + poff[18], *dec_b0  = P + poff[19];
  const bf16 *dec_w1  = P + poff[20], *dec_b1  = P + poff[21];
  const bf16 *dec_w2  = P + poff[22], *dec_b2  = P + poff[23];
  const bf16 *dec_w3  = P + poff[24], *dec_b3  = P + poff[25];

  bf16* wt0 = WT;
  bf16* wt1 = wt0 + 1048576;
  bf16* wt2 = wt1 + 524288;
  bf16* wt3 = wt2 + 131072;
  k_wtrans<<<(1048576 + 255) / 256, 256, 0, stream>>>(dec_w0, wt0, 256, 8, 256, 256);
  k_wtrans<<<(524288 + 255) / 256, 256, 0, stream>>>(dec_w1, wt1, 256, 8, 128, 128);
  k_wtrans<<<(131072 + 255) / 256, 256, 0, stream>>>(dec_w2, wt2, 128, 7, 64, 64);
  k_wtrans<<<(3072 + 255) / 256, 256, 0, stream>>>(dec_w3, wt3, 64, 6, 3, 3);
  k_cnorm<<<32, 256, 0, stream>>>(codebook, cnorm);

  // patch embedding: split-K depth 2 (Kc=1536, dbuf) -> bf16 partials + reduce
  k_im2col<<<dim3(3, 8192), 128, 0, stream>>>(d_in[0], A_im, flag);
  gemm_t<4, 2, 128, true><<<dim3(2, 128, 2), 256, 0, stream>>>(
      A_im, patch_w, nullptr, nullptr, Pfb, nullptr, nullptr, 8192, 256, 3072, 1536);
  k_lnred<false><<<8192, 256, 0, stream>>>(
      Pfb, patch_b, nullptr, nullptr, nullptr, nullptr, nullptr, hbuf, 2);

  // transformer encoder: fused attention block + FF path (ff2 split-K depth 2);
  // layer 5's lnred additionally applies lnf
  for (int l = 0; l < 6; ++l) {
    k_fat1<<<256, 256, 0, stream>>>(
        hbuf, qkv_w + (size_t)l * 768 * 256, qkv_b + l * 768,
        out_w + (size_t)l * 256 * 256, out_b + l * 256,
        ln1_w + l * 256, ln1_b + l * 256);
    gemm_t<1, 2, 256, false><<<dim3(4, 128, 1), 256, 0, stream>>>(
        hbuf, ff1_w + (size_t)l * 1024 * 256, ff1_b + l * 1024, nullptr, ffb,
        nullptr, nullptr, 8192, 1024, 256, 256);
    gemm_t<4, 2, 128, false><<<dim3(2, 128, 2), 256, 0, stream>>>(
        ffb, ff2_w + (size_t)l * 256 * 1024, nullptr, nullptr, Pfb,
        nullptr, nullptr, 8192, 256, 1024, 512);
    k_lnred<true><<<8192, 256, 0, stream>>>(
        Pfb, ff2_b + l * 256, hbuf, ln2_w + l * 256, ln2_b + l * 256,
        (l == 5) ? lnf_w : nullptr, (l == 5) ? lnf_b : nullptr, hbuf, 2);
  }

  // VQ via MFMA + packed-key argmin (proven FM=2 x BN=256 config)
  gemm_t<3, 2, 256, false><<<dim3(32, 128, 1), 256, 0, stream>>>(
      hbuf, codebook, nullptr, nullptr, nullptr, cnorm, ku, 8192, 8192, 256, 256);
  k_vqmerge<<<32, 256, 0, stream>>>(ku, idx, 8192, 32);

  k_zborder<<<(32 * 68 * 32 + 255) / 256, 256, 0, stream>>>(a0, 18, 256, 32);
  k_gather<<<8192, 256, 0, stream>>>(hbuf, codebook, idx, a0, lsum);
  k_loss<<<1, 256, 0, stream>>>(lsum, lossout);
  k_zborder<<<(32 * 132 * 32 + 255) / 256, 256, 0, stream>>>(a1, 34, 256, 32);
  k_zborder<<<(32 * 260 * 16 + 255) / 256, 256, 0, stream>>>(a2, 66, 128, 32);
  k_zborder<<<(16 * 516 * 8 + 255) / 256, 256, 0, stream>>>(a3, 130, 64, 16);

  // decoder
  convt64<<<dim3(4, 64, 4), 256, 0, stream>>>(a0, wt0, dec_b0, a1, 16, 4, 256, 8, 256);
  convt64<<<dim3(2, 256, 4), 256, 0, stream>>>(a1, wt1, dec_b1, a2, 32, 5, 256, 8, 128);
  for (int c = 0; c < 2; ++c) {
    const bf16* a2c = a2 + (size_t)c * 16 * 66 * 66 * 128;
    convt64<<<dim3(1, 512, 4), 256, 0, stream>>>(a2c, wt2, dec_b2, a3, 64, 6, 128, 7, 64);
    k_dec3<<<dim3(256, 4, 16), 256, 0, stream>>>(a3, wt3, dec_b3, xhat, c * 16);
  }
}

// Round 26
// 960.649 us; speedup vs baseline: 1.0062x; 1.0062x over previous
//
#include <hip/hip_runtime.h>
#include <hip/hip_bf16.h>
#include <math.h>

typedef __hip_bfloat16 bf16;
typedef unsigned int u32;
typedef unsigned long long u64;
using short8 = __attribute__((ext_vector_type(8))) short;
using f32x4  = __attribute__((ext_vector_type(4))) float;

__device__ __forceinline__ float b2f(bf16 v){ return __bfloat162float(v); }
__device__ __forceinline__ bf16  f2b(float v){ return __float2bfloat16(v); }
__device__ __forceinline__ float plo(u32 u){ return __uint_as_float(u << 16); }
__device__ __forceinline__ float phi(u32 u){ return __uint_as_float(u & 0xffff0000u); }

__device__ __forceinline__ void gld16(const void* g, void* l)
{
  __builtin_amdgcn_global_load_lds(
      (const __attribute__((address_space(1))) u32*)g,
      (__attribute__((address_space(3))) u32*)l, 16, 0, 0);
}

// ---- dtype probe ----
__global__ void k_detect(const u32* probe, int* flag)
{
  if (threadIdx.x == 0 && blockIdx.x == 0)
    *flag = (*probe == 0x3F800000u) ? 0 : 1;
}

// ---- all param arrays -> canonical bf16, one dispatch ----
struct PPack { const void* s[25]; u32 off[26]; };
__global__ __launch_bounds__(256) void k_convall(PPack pp, bf16* P, const int* flag)
{
  const u32 i = blockIdx.x * 256 + threadIdx.x;
  if (i >= pp.off[25]) return;
  int lo = 0, hi = 25;
  while (hi - lo > 1) { const int mid = (lo + hi) >> 1; if (i >= pp.off[mid]) lo = mid; else hi = mid; }
  const u32 j = i - pp.off[lo];
  P[i] = *flag ? ((const bf16*)pp.s[lo])[j] : f2b(((const float*)pp.s[lo])[j]);
}

// ---- zero only the 1-pixel border ring of a padded channels-last buffer ----
__global__ __launch_bounds__(256) void k_zborder(bf16* buf, int Hp, int C, int nimg)
{
  const int per = 4 * Hp - 4;
  const int c8 = C >> 3;
  const int total = nimg * per * c8;
  const int i = blockIdx.x * 256 + threadIdx.x;
  if (i >= total) return;
  const int ch8 = i % c8;
  const int pb = i / c8;
  const int img = pb / per;
  const int b = pb - img * per;
  int y, x;
  if (b < Hp) { y = 0; x = b; }
  else if (b < 2 * Hp) { y = Hp - 1; x = b - Hp; }
  else {
    const int r = b - 2 * Hp;
    const int side = r / (Hp - 2);
    y = 1 + r - side * (Hp - 2);
    x = side ? (Hp - 1) : 0;
  }
  uint4 z = {0, 0, 0, 0};
  *reinterpret_cast<uint4*>(buf + (((size_t)img * Hp + y) * Hp + x) * C + ch8 * 8) = z;
}

// ---- vectorized im2col: x (f32 or bf16) -> A_im bf16 (8192 x 3072) ----
__global__ __launch_bounds__(128) void k_im2col(const void* x, bf16* A, const int* flag)
{
  const int m = blockIdx.y;
  const int k8 = blockIdx.x * 128 + threadIdx.x;
  const int k = k8 * 8;
  const int b = m >> 8, n = m & 255;
  const int gy = n >> 4, gx = n & 15;
  const int c = k >> 10, r = (k >> 5) & 31, pp = k & 31;
  const size_t src = (((size_t)(b * 3 + c) * 512) + gy * 32 + r) * 512 + gx * 32 + pp;
  bf16 ov[8];
  if (*flag) {
    const bf16* xp = (const bf16*)x + src;
    #pragma unroll
    for (int i = 0; i < 8; ++i) ov[i] = xp[i];
  } else {
    const float4 v0 = *reinterpret_cast<const float4*>((const float*)x + src);
    const float4 v1 = *reinterpret_cast<const float4*>((const float*)x + src + 4);
    ov[0]=f2b(v0.x); ov[1]=f2b(v0.y); ov[2]=f2b(v0.z); ov[3]=f2b(v0.w);
    ov[4]=f2b(v1.x); ov[5]=f2b(v1.y); ov[6]=f2b(v1.z); ov[7]=f2b(v1.w);
  }
  *reinterpret_cast<uint4*>(A + (size_t)m * 3072 + k) = *reinterpret_cast<const uint4*>(ov);
}

// === MFMA GEMM, BM=FM*32, BN in {128,256}; optional dbuf; split-K via grid.z ===
template<int EPI, int FM, int BN, bool DB>
__global__ __launch_bounds__(256, 2) void gemm_t(
    const bf16* __restrict__ A, const bf16* __restrict__ Bw,
    const bf16* __restrict__ bias, const bf16* res, bf16* C,
    const float* __restrict__ cnorm, u64* __restrict__ ku,
    int M, int N, int K, int Kc)
{
  constexpr int BM = FM * 32;
  constexpr int FN = BN / 32;
  __shared__ alignas(16) bf16 As[DB ? 2 : 1][BM * 64];
  __shared__ alignas(16) bf16 Bs[DB ? 2 : 1][BN * 64];
  const int tid = threadIdx.x;
  const int bn = blockIdx.x * BN, bm = blockIdx.y * BM;
  const int z = blockIdx.z;
  const int kb = z * Kc;
  const int l = tid & 63, w = tid >> 6;
  const int wm = w >> 1, wn = w & 1;
  const int lg = l >> 4, lr = l & 15;
  const int sr8 = l >> 3;
  const int sch = (l & 7) ^ sr8;
  f32x4 acc[FM][FN];
  #pragma unroll
  for (int fm = 0; fm < FM; ++fm)
    #pragma unroll
    for (int fn = 0; fn < FN; ++fn) acc[fm][fn] = (f32x4){0.f, 0.f, 0.f, 0.f};

  auto stage = [&](int bb, int k0) {
    char* ab = (char*)As[bb];
    char* bp = (char*)Bs[bb];
    #pragma unroll
    for (int it = 0; it < FM; ++it) {
      const int r = w * 8 + it * 32 + sr8;
      gld16(A + (size_t)(bm + r) * K + k0 + sch * 8, ab + w * 1024 + it * 4096);
    }
    #pragma unroll
    for (int it = 0; it < BN / 32; ++it) {
      const int r = w * 8 + it * 32 + sr8;
      gld16(Bw + (size_t)(bn + r) * K + k0 + sch * 8, bp + w * 1024 + it * 4096);
    }
  };
  auto compute = [&](int bb) {
    const char* ab = (const char*)As[bb];
    const char* bp = (const char*)Bs[bb];
    #pragma unroll
    for (int ks = 0; ks < 2; ++ks) {
      short8 af[FM], bfr[FN];
      #pragma unroll
      for (int fm = 0; fm < FM; ++fm) {
        const int r = wm * (FM * 16) + fm * 16 + lr;
        af[fm] = *reinterpret_cast<const short8*>(ab + r * 128 + (((lg + ks * 4) ^ (r & 7)) * 16));
      }
      #pragma unroll
      for (int fn = 0; fn < FN; ++fn) {
        const int r = wn * (BN / 2) + fn * 16 + lr;
        bfr[fn] = *reinterpret_cast<const short8*>(bp + r * 128 + (((lg + ks * 4) ^ (r & 7)) * 16));
      }
      #pragma unroll
      for (int fm = 0; fm < FM; ++fm)
        #pragma unroll
        for (int fn = 0; fn < FN; ++fn)
          acc[fm][fn] = __builtin_amdgcn_mfma_f32_16x16x32_bf16(af[fm], bfr[fn], acc[fm][fn], 0, 0, 0);
    }
  };

  const int nt = Kc >> 6;
  if (DB) {
    stage(0, kb);
    __syncthreads();
    for (int t = 0; t < nt; ++t) {
      const int cur = t & 1;
      if (t + 1 < nt) stage(cur ^ 1, kb + ((t + 1) << 6));
      compute(cur);
      __syncthreads();
    }
  } else {
    for (int t = 0; t < nt; ++t) {
      if (t) __syncthreads();
      stage(0, kb + (t << 6));
      __syncthreads();
      compute(0);
    }
  }

  if (EPI == 3) {
    __shared__ u64 skey[BM][2];
    float cn[FN];
    #pragma unroll
    for (int fn = 0; fn < FN; ++fn) cn[fn] = cnorm[bn + wn * (BN / 2) + fn * 16 + lr];
    #pragma unroll
    for (int fm = 0; fm < FM; ++fm) {
      #pragma unroll
      for (int r = 0; r < 4; ++r) {
        u64 best = ~0ull;
        #pragma unroll
        for (int fn = 0; fn < FN; ++fn) {
          const int col = bn + wn * (BN / 2) + fn * 16 + lr;
          const float d = cn[fn] - 2.0f * acc[fm][fn][r];
          u32 u = __float_as_uint(d);
          u = (u & 0x80000000u) ? ~u : (u | 0x80000000u);
          const u64 key = ((u64)u << 32) | (u32)col;
          best = key < best ? key : best;
        }
        #pragma unroll
        for (int mk = 1; mk < 16; mk <<= 1) {
          const u64 o = __shfl_xor(best, mk, 64);
          best = o < best ? o : best;
        }
        if (lr == 0) skey[wm * (FM * 16) + fm * 16 + lg * 4 + r][wn] = best;
      }
    }
    __syncthreads();
    if (tid < BM) {
      const u64 a = skey[tid][0], b = skey[tid][1];
      ku[(size_t)blockIdx.x * M + bm + tid] = a < b ? a : b;
    }
  } else if (EPI == 4) {
    #pragma unroll
    for (int fm = 0; fm < FM; ++fm) {
      const int m0 = bm + wm * (FM * 16) + fm * 16 + lg * 4;
      #pragma unroll
      for (int fn = 0; fn < FN; ++fn) {
        const int n = bn + wn * (BN / 2) + fn * 16 + lr;
        #pragma unroll
        for (int r = 0; r < 4; ++r)
          C[((size_t)z * M + m0 + r) * N + n] = f2b(acc[fm][fn][r]);
      }
    }
  } else {
    #pragma unroll
    for (int fm = 0; fm < FM; ++fm) {
      const int m0 = bm + wm * (FM * 16) + fm * 16 + lg * 4;
      #pragma unroll
      for (int fn = 0; fn < FN; ++fn) {
        const int n = bn + wn * (BN / 2) + fn * 16 + lr;
        const float bs = b2f(bias[n]);
        #pragma unroll
        for (int r = 0; r < 4; ++r) {
          float v = acc[fm][fn][r] + bs;
          if (EPI == 1) v = 0.5f * v * (1.0f + erff(v * 0.70710678118654752f));
          if (EPI == 2) v += b2f(res[(size_t)(m0 + r) * N + n]);
          C[(size_t)(m0 + r) * N + n] = f2b(v);
        }
      }
    }
  }
}

// ====== fused per-bt transformer phase 1: qkv -> attention -> attnout+res+LN1 ======
__global__ __launch_bounds__(256, 1) void k_fat1(
    bf16* __restrict__ hbuf,
    const bf16* __restrict__ Wqkv, const bf16* __restrict__ Bqkv,
    const bf16* __restrict__ Wo, const bf16* __restrict__ Bo,
    const bf16* __restrict__ lw, const bf16* __restrict__ lb)
{
  __shared__ alignas(16) bf16 hs[32 * 256];
  __shared__ alignas(16) bf16 ao[32 * 256];
  __shared__ alignas(16) bf16 astage[128 * 64];
  __shared__ bf16 att[3 * 9216];
  __shared__ float ps[32][33];
  __shared__ float rs[32];
  __shared__ float psum[32][4], psq[32][4];
  __shared__ float mstat[32], istat[32];

  const int bt = blockIdx.x;
  const int tid = threadIdx.x;
  const int l = tid & 63, w = tid >> 6;
  const int lg = l >> 4, lr = l & 15;
  const int sr8 = l >> 3;
  const int sch = (l & 7) ^ sr8;
  char* hsb = (char*)hs;
  char* aob = (char*)ao;
  char* asb = (char*)astage;

  #pragma unroll
  for (int call = 0; call < 4; ++call) {
    const int id = call * 256 + tid;
    const int s = id >> 5, within = id & 31;
    const int grp = within >> 3, c = within & 7;
    gld16(hbuf + (size_t)(s * 256 + bt) * 256 + grp * 64 + ((c ^ (s & 7)) * 8),
          hsb + call * 4096 + w * 1024);
  }

  for (int at = 0; at < 6; ++at) {
    f32x4 acc[2][2];
    #pragma unroll
    for (int fm = 0; fm < 2; ++fm)
      #pragma unroll
      for (int fn = 0; fn < 2; ++fn) acc[fm][fn] = (f32x4){0.f, 0.f, 0.f, 0.f};
    for (int kst = 0; kst < 4; ++kst) {
      __syncthreads();
      #pragma unroll
      for (int it = 0; it < 4; ++it) {
        const int r = w * 8 + it * 32 + sr8;
        gld16(Wqkv + (size_t)(at * 128 + r) * 256 + kst * 64 + sch * 8,
              asb + w * 1024 + it * 4096);
      }
      __syncthreads();
      #pragma unroll
      for (int ks = 0; ks < 2; ++ks) {
        short8 af[2], bfr[2];
        #pragma unroll
        for (int fm = 0; fm < 2; ++fm) {
          const int r = w * 32 + fm * 16 + lr;
          af[fm] = *reinterpret_cast<const short8*>(asb + r * 128 + (((lg + ks * 4) ^ (r & 7)) * 16));
        }
        #pragma unroll
        for (int fn = 0; fn < 2; ++fn) {
          const int sr = fn * 16 + lr;
          bfr[fn] = *reinterpret_cast<const short8*>(hsb + sr * 512 + kst * 128 + (((lg + ks * 4) ^ (sr & 7)) * 16));
        }
        #pragma unroll
        for (int fm = 0; fm < 2; ++fm)
          #pragma unroll
          for (int fn = 0; fn < 2; ++fn)
            acc[fm][fn] = __builtin_amdgcn_mfma_f32_16x16x32_bf16(af[fm], bfr[fn], acc[fm][fn], 0, 0, 0);
      }
    }
    #pragma unroll
    for (int fm = 0; fm < 2; ++fm) {
      #pragma unroll
      for (int fn = 0; fn < 2; ++fn) {
        const int s = fn * 16 + lr;
        #pragma unroll
        for (int r = 0; r < 4; ++r) {
          const int n = at * 128 + w * 32 + fm * 16 + lg * 4 + r;
          const int p = n >> 8, rem = n & 255;
          att[p * 9216 + (rem >> 5) * 1152 + s * 36 + (rem & 31)] =
              f2b(acc[fm][fn][r] + b2f(Bqkv[n]));
        }
      }
    }
  }
  __syncthreads();

  const int s_a = tid >> 3, j_a = tid & 7;
  for (int hd = 0; hd < 8; ++hd) {
    const bf16* qrow = att + hd * 1152 + s_a * 36;
    float sc[4];
    #pragma unroll
    for (int e = 0; e < 4; ++e) {
      const int t = j_a + 8 * e;
      const bf16* krow = att + 9216 + hd * 1152 + t * 36;
      float v = 0.f;
      #pragma unroll
      for (int dd = 0; dd < 32; ++dd) v += b2f(qrow[dd]) * b2f(krow[dd]);
      sc[e] = v * 0.17677669529663687f;
    }
    float mx = fmaxf(fmaxf(sc[0], sc[1]), fmaxf(sc[2], sc[3]));
    #pragma unroll
    for (int mk = 1; mk < 8; mk <<= 1) mx = fmaxf(mx, __shfl_xor(mx, mk, 64));
    float sm = 0.f; float ex[4];
    #pragma unroll
    for (int e = 0; e < 4; ++e) { ex[e] = expf(sc[e] - mx); sm += ex[e]; }
    #pragma unroll
    for (int mk = 1; mk < 8; mk <<= 1) sm += __shfl_xor(sm, mk, 64);
    #pragma unroll
    for (int e = 0; e < 4; ++e) ps[s_a][j_a + 8 * e] = ex[e];
    if (j_a == 0) rs[s_a] = 1.0f / sm;
    __syncthreads();
    const float rinv = rs[s_a];
    float av[4];
    #pragma unroll
    for (int e = 0; e < 4; ++e) {
      const int dd = j_a * 4 + e;
      float a = 0.f;
      #pragma unroll
      for (int t = 0; t < 32; ++t)
        a += ps[s_a][t] * b2f(att[2 * 9216 + hd * 1152 + t * 36 + dd]);
      av[e] = a * rinv;
    }
    alignas(8) bf16 ov[4];
    #pragma unroll
    for (int e = 0; e < 4; ++e) ov[e] = f2b(av[e]);
    const int clog = (hd & 1) * 4 + (j_a >> 1);
    *reinterpret_cast<ushort4*>(aob + s_a * 512 + (hd >> 1) * 128 +
        ((clog ^ (s_a & 7)) * 16) + (j_a & 1) * 8) =
        *reinterpret_cast<const ushort4*>(ov);
    __syncthreads();
  }

  float vals[2][2][2][4];
  for (int at = 0; at < 2; ++at) {
    f32x4 acc[2][2];
    #pragma unroll
    for (int fm = 0; fm < 2; ++fm)
      #pragma unroll
      for (int fn = 0; fn < 2; ++fn) acc[fm][fn] = (f32x4){0.f, 0.f, 0.f, 0.f};
    for (int kst = 0; kst < 4; ++kst) {
      __syncthreads();
      #pragma unroll
      for (int it = 0; it < 4; ++it) {
        const int r = w * 8 + it * 32 + sr8;
        gld16(Wo + (size_t)(at * 128 + r) * 256 + kst * 64 + sch * 8,
              asb + w * 1024 + it * 4096);
      }
      __syncthreads();
      #pragma unroll
      for (int ks = 0; ks < 2; ++ks) {
        short8 af[2], bfr[2];
        #pragma unroll
        for (int fm = 0; fm < 2; ++fm) {
          const int r = w * 32 + fm * 16 + lr;
          af[fm] = *reinterpret_cast<const short8*>(asb + r * 128 + (((lg + ks * 4) ^ (r & 7)) * 16));
        }
        #pragma unroll
        for (int fn = 0; fn < 2; ++fn) {
          const int sr = fn * 16 + lr;
          bfr[fn] = *reinterpret_cast<const short8*>(aob + sr * 512 + kst * 128 + (((lg + ks * 4) ^ (sr & 7)) * 16));
        }
        #pragma unroll
        for (int fm = 0; fm < 2; ++fm)
          #pragma unroll
          for (int fn = 0; fn < 2; ++fn)
            acc[fm][fn] = __builtin_amdgcn_mfma_f32_16x16x32_bf16(af[fm], bfr[fn], acc[fm][fn], 0, 0, 0);
      }
    }
    #pragma unroll
    for (int fm = 0; fm < 2; ++fm)
      #pragma unroll
      for (int fn = 0; fn < 2; ++fn)
        #pragma unroll
        for (int r = 0; r < 4; ++r) vals[at][fm][fn][r] = acc[fm][fn][r];
  }

  float s1[2] = {0.f, 0.f}, s2[2] = {0.f, 0.f};
  #pragma unroll
  for (int at = 0; at < 2; ++at) {
    #pragma unroll
    for (int fm = 0; fm < 2; ++fm) {
      const int n4 = at * 128 + w * 32 + fm * 16 + lg * 4;
      #pragma unroll
      for (int fn = 0; fn < 2; ++fn) {
        const int s = fn * 16 + lr;
        const ushort4 hr = *reinterpret_cast<const ushort4*>(
            hsb + s * 512 + (n4 >> 6) * 128 + ((((n4 >> 3) & 7) ^ (s & 7)) * 16) + (n4 & 7) * 2);
        const bf16* hb = reinterpret_cast<const bf16*>(&hr);
        #pragma unroll
        for (int r = 0; r < 4; ++r) {
          const float v = vals[at][fm][fn][r] + b2f(Bo[n4 + r]) + b2f(hb[r]);
          vals[at][fm][fn][r] = v;
          s1[fn] += v;
          s2[fn] += v * v;
        }
      }
    }
  }
  #pragma unroll
  for (int fn = 0; fn < 2; ++fn) {
    float a = s1[fn], b = s2[fn];
    a += __shfl_xor(a, 16, 64); a += __shfl_xor(a, 32, 64);
    b += __shfl_xor(b, 16, 64); b += __shfl_xor(b, 32, 64);
    if (lg == 0) { psum[fn * 16 + lr][w] = a; psq[fn * 16 + lr][w] = b; }
  }
  __syncthreads();
  if (tid < 32) {
    float sa = 0.f, sb = 0.f;
    #pragma unroll
    for (int k = 0; k < 4; ++k) { sa += psum[tid][k]; sb += psq[tid][k]; }
    const float m = sa * (1.0f / 256.0f);
    mstat[tid] = m;
    istat[tid] = 1.0f / sqrtf(sb * (1.0f / 256.0f) - m * m + 1e-5f);
  }
  __syncthreads();
  #pragma unroll
  for (int at = 0; at < 2; ++at) {
    #pragma unroll
    for (int fm = 0; fm < 2; ++fm) {
      const int n4 = at * 128 + w * 32 + fm * 16 + lg * 4;
      #pragma unroll
      for (int fn = 0; fn < 2; ++fn) {
        const int s = fn * 16 + lr;
        const float m = mstat[s], inv = istat[s];
        alignas(8) bf16 ov[4];
        #pragma unroll
        for (int r = 0; r < 4; ++r)
          ov[r] = f2b((vals[at][fm][fn][r] - m) * inv * b2f(lw[n4 + r]) + b2f(lb[n4 + r]));
        *reinterpret_cast<ushort4*>(hbuf + (size_t)(s * 256 + bt) * 256 + n4) =
            *reinterpret_cast<const ushort4*>(ov);
      }
    }
  }
}

// ---- split-K reduce (bf16 partials) + bias (+res) + LN (+optional 2nd LN) ----
template<bool DOLN>
__global__ __launch_bounds__(256) void k_lnred(
    const bf16* __restrict__ Pf, const bf16* __restrict__ bias,
    const bf16* res, const bf16* __restrict__ lw, const bf16* __restrict__ lb,
    const bf16* lw2, const bf16* lb2,
    bf16* h, int kc)
{
  __shared__ float red[256];
  __shared__ float stat[2];
  const int row = blockIdx.x, d = threadIdx.x;
  float s = 0.f;
  for (int z = 0; z < kc; ++z) s += b2f(Pf[((size_t)z * 8192 + row) * 256 + d]);
  s += b2f(bias[d]);
  if (res) s += b2f(res[(size_t)row * 256 + d]);
  if (!DOLN) { h[(size_t)row * 256 + d] = f2b(s); return; }
  red[d] = s;
  __syncthreads();
  for (int off = 128; off > 0; off >>= 1) {
    if (d < off) red[d] += red[d + off];
    __syncthreads();
  }
  if (d == 0) stat[0] = red[0] * (1.0f / 256.0f);
  __syncthreads();
  float m = stat[0];
  red[d] = (s - m) * (s - m);
  __syncthreads();
  for (int off = 128; off > 0; off >>= 1) {
    if (d < off) red[d] += red[d + off];
    __syncthreads();
  }
  if (d == 0) stat[1] = 1.0f / sqrtf(red[0] * (1.0f / 256.0f) + 1e-5f);
  __syncthreads();
  float y = (s - m) * stat[1] * b2f(lw[d]) + b2f(lb[d]);
  if (lw2) {
    __syncthreads();
    red[d] = y;
    __syncthreads();
    for (int off = 128; off > 0; off >>= 1) {
      if (d < off) red[d] += red[d + off];
      __syncthreads();
    }
    if (d == 0) stat[0] = red[0] * (1.0f / 256.0f);
    __syncthreads();
    m = stat[0];
    red[d] = (y - m) * (y - m);
    __syncthreads();
    for (int off = 128; off > 0; off >>= 1) {
      if (d < off) red[d] += red[d + off];
      __syncthreads();
    }
    if (d == 0) stat[1] = 1.0f / sqrtf(red[0] * (1.0f / 256.0f) + 1e-5f);
    __syncthreads();
    y = (y - m) * stat[1] * b2f(lw2[d]) + b2f(lb2[d]);
  }
  h[(size_t)row * 256 + d] = f2b(y);
}

// ---- VQ merge over u64 keys (deterministic) ----
__global__ __launch_bounds__(256) void k_vqmerge(
    const u64* __restrict__ ku, int* __restrict__ idx, int M, int NB)
{
  const int r = blockIdx.x * 256 + threadIdx.x;
  if (r >= M) return;
  u64 best = ku[r];
  for (int nb = 1; nb < NB; ++nb) {
    const u64 k = ku[(size_t)nb * M + r];
    best = k < best ? k : best;
  }
  idx[r] = (int)(best & 0xFFFFFFFFull);
}

// ---- codebook norms ----
__global__ __launch_bounds__(256) void k_cnorm(const bf16* __restrict__ cb, float* __restrict__ cn)
{
  const int j = blockIdx.x * 256 + threadIdx.x;
  const u32* p = (const u32*)(cb + (size_t)j * 256);
  float s = 0.f;
  for (int k = 0; k < 128; ++k) {
    const u32 v = p[k];
    const float a = plo(v), b = phi(v);
    s += a * a + b * b;
  }
  cn[j] = s;
}

// ---- gather codebook -> padded channels-last a0 + per-row loss partials ----
__global__ __launch_bounds__(256) void k_gather(
    const bf16* h, const bf16* cb, const int* idx, bf16* a0, float* lsum)
{
  __shared__ float red[256];
  const int row = blockIdx.x, d = threadIdx.x;
  const int code = idx[row] & 8191;
  const float q = b2f(cb[(size_t)code * 256 + d]);
  const float x = b2f(h[(size_t)row * 256 + d]);
  red[d] = (q - x) * (q - x);
  __syncthreads();
  for (int off = 128; off > 0; off >>= 1) {
    if (d < off) red[d] += red[d + off];
    __syncthreads();
  }
  if (d == 0) lsum[row] = red[0];
  const int b = row >> 8, n = row & 255;
  const int y = n >> 4, xc = n & 15;
  a0[(((size_t)b * 18 + y + 1) * 18 + (xc + 1)) * 256 + d] = f2b(q);
}

// ---- deterministic loss reduce -> f32 scalar ----
__global__ __launch_bounds__(256) void k_loss(const float* lsum, float* out)
{
  __shared__ float red[256];
  const int tid = threadIdx.x;
  float v = 0.f;
  for (int i = 0; i < 32; ++i) v += lsum[tid + 256 * i];
  red[tid] = v;
  __syncthreads();
  for (int off = 128; off > 0; off >>= 1) {
    if (tid < off) red[tid] += red[tid + off];
    __syncthreads();
  }
  if (tid == 0)
    out[0] = red[0] * (1.25f / 2097152.0f);
}

// ---- decoder weight transform ----
__global__ __launch_bounds__(256) void k_wtrans(
    const bf16* __restrict__ w, bf16* __restrict__ wt,
    int Cin, int lCin, int CoutR, int CoutP)
{
  const int K = Cin << 2;
  const int total = 4 * CoutP * K;
  const int i = blockIdx.x * 256 + threadIdx.x;
  if (i >= total) return;
  const int p = i / (CoutP * K);
  const int rem = i - p * (CoutP * K);
  const int co = rem / K;
  const int k = rem - co * K;
  const int tap = k >> lCin, ci = k - (tap << lCin);
  const int py = p >> 1, px = p & 1, ty = tap >> 1, tx = tap & 1;
  bf16 v = f2b(0.f);
  if (co < CoutR)
    v = w[(((size_t)ci * CoutR + co) * 4 + py + 2 * ty) * 4 + px + 2 * tx];
  wt[i] = v;
}

// ====== decoder convT implicit MFMA GEMM, double-buffered 2-phase ======
__global__ __launch_bounds__(256, 2) void convt64(
    const bf16* __restrict__ in, const bf16* __restrict__ Wt,
    const bf16* __restrict__ bias, bf16* __restrict__ outp,
    int H, int lH, int Cin, int lCin, int Cout)
{
  __shared__ alignas(16) bf16 As[2][128 * 64];
  __shared__ alignas(16) bf16 Bs[2][64 * 64];
  const int tid = threadIdx.x;
  const int pz = blockIdx.z;
  const int py = pz >> 1, px = pz & 1;
  const int K = Cin << 2;
  const int bn = blockIdx.x * 64, bm = blockIdx.y * 128;
  const bf16* Bw = Wt + (size_t)pz * Cout * K;
  const int l = tid & 63, w = tid >> 6;
  const int wm = w >> 1, wn = w & 1;
  const int lg = l >> 4, lr = l & 15;
  const int sr8 = l >> 3;
  const int sch = (l & 7) ^ sr8;
  const int Hp = H + 2;
  f32x4 acc[4][2];
  #pragma unroll
  for (int fm = 0; fm < 4; ++fm)
    #pragma unroll
    for (int fn = 0; fn < 2; ++fn) acc[fm][fn] = (f32x4){0.f, 0.f, 0.f, 0.f};

  size_t pixbase[4];
  #pragma unroll
  for (int it = 0; it < 4; ++it) {
    const int m = bm + w * 8 + it * 32 + sr8;
    const int b = m >> (2 * lH);
    const int rem = m & ((1 << (2 * lH)) - 1);
    const int jj = rem >> lH, ii = rem & (H - 1);
    pixbase[it] = ((size_t)(b * Hp + jj) * Hp + ii);
  }

  auto stage = [&](int bb, int k0) {
    char* ab = (char*)As[bb];
    char* bp = (char*)Bs[bb];
    const int tap = k0 >> lCin;
    const int ty = tap >> 1, tx = tap & 1;
    const int sy = (1 - py) + (1 - ty);
    const int sx = (1 - px) + (1 - tx);
    const int ci0 = (k0 - (tap << lCin)) + sch * 8;
    #pragma unroll
    for (int it = 0; it < 4; ++it)
      gld16(in + (pixbase[it] + (size_t)sy * Hp + sx) * Cin + ci0,
            ab + w * 1024 + it * 4096);
    #pragma unroll
    for (int it = 0; it < 2; ++it) {
      const int r = w * 8 + it * 32 + sr8;
      gld16(Bw + (size_t)(bn + r) * K + k0 + sch * 8, bp + w * 1024 + it * 4096);
    }
  };

  const int nt = K >> 6;
  stage(0, 0);
  __syncthreads();
  for (int t = 0; t < nt; ++t) {
    const int cur = t & 1;
    if (t + 1 < nt) stage(cur ^ 1, (t + 1) << 6);
    const char* ab = (const char*)As[cur];
    const char* bb = (const char*)Bs[cur];
    #pragma unroll
    for (int ks = 0; ks < 2; ++ks) {
      short8 af[4], bfr[2];
      #pragma unroll
      for (int fm = 0; fm < 4; ++fm) {
        const int r = wm * 64 + fm * 16 + lr;
        af[fm] = *reinterpret_cast<const short8*>(ab + r * 128 + (((lg + ks * 4) ^ (r & 7)) * 16));
      }
      #pragma unroll
      for (int fn = 0; fn < 2; ++fn) {
        const int r = wn * 32 + fn * 16 + lr;
        bfr[fn] = *reinterpret_cast<const short8*>(bb + r * 128 + (((lg + ks * 4) ^ (r & 7)) * 16));
      }
      #pragma unroll
      for (int fm = 0; fm < 4; ++fm)
        #pragma unroll
        for (int fn = 0; fn < 2; ++fn)
          acc[fm][fn] = __builtin_amdgcn_mfma_f32_16x16x32_bf16(af[fm], bfr[fn], acc[fm][fn], 0, 0, 0);
    }
    __syncthreads();
  }

  const int Ho = 2 * H, Hop = Ho + 2;
  #pragma unroll
  for (int fm = 0; fm < 4; ++fm) {
    const int m0 = bm + wm * 64 + fm * 16 + lg * 4;
    #pragma unroll
    for (int fn = 0; fn < 2; ++fn) {
      const int n = bn + wn * 32 + fn * 16 + lr;
      #pragma unroll
      for (int r = 0; r < 4; ++r) {
        const int m = m0 + r;
        const int b = m >> (2 * lH);
        const int rem = m & ((1 << (2 * lH)) - 1);
        const int jj = rem >> lH, ii = rem & (H - 1);
        const int oy = 2 * jj + (1 - py), ox = 2 * ii + (1 - px);
        const float v = fmaxf(acc[fm][fn][r] + b2f(bias[n]), 0.f);
        outp[((size_t)(b * Hop + oy + 1) * Hop + ox + 1) * Cout + n] = f2b(v);
      }
    }
  }
}

// ---- final decoder layer (Cout=3): coalesced vector kernel ----
__global__ __launch_bounds__(256) void k_dec3(
    const bf16* __restrict__ a3, const bf16* __restrict__ wt3,
    const bf16* __restrict__ bias, float* __restrict__ xhat, int chunkBase)
{
  __shared__ float wl[3][264];
  const int tid = threadIdx.x;
  const int pz = blockIdx.y;
  const int py = pz >> 1, px = pz & 1;
  for (int i = tid; i < 768; i += 256) {
    const int co = i >> 8, k = i & 255;
    wl[co][k] = b2f(wt3[(pz * 3 + co) * 256 + k]);
  }
  __syncthreads();
  const int b = blockIdx.z;
  const int p = blockIdx.x * 64 + (tid >> 2);
  const int jj = p >> 7, ii = p & 127;
  const int ch4 = tid & 3;
  float a0 = 0.f, a1 = 0.f, a2 = 0.f;
  #pragma unroll
  for (int ty = 0; ty < 2; ++ty) {
    #pragma unroll
    for (int tx = 0; tx < 2; ++tx) {
      const int sy = (1 - py) + (1 - ty), sx = (1 - px) + (1 - tx);
      const int tap = ty * 2 + tx;
      const u32* ip = (const u32*)(a3 + ((size_t)(b * 130 + jj + sy) * 130 + ii + sx) * 64) + ch4 * 8;
      const float* w0 = &wl[0][tap * 64 + ch4 * 16];
      const float* w1 = &wl[1][tap * 64 + ch4 * 16];
      const float* w2 = &wl[2][tap * 64 + ch4 * 16];
      #pragma unroll
      for (int kk = 0; kk < 8; ++kk) {
        const u32 v = ip[kk];
        const float e0 = plo(v), e1 = phi(v);
        a0 += e0 * w0[2 * kk] + e1 * w0[2 * kk + 1];
        a1 += e0 * w1[2 * kk] + e1 * w1[2 * kk + 1];
        a2 += e0 * w2[2 * kk] + e1 * w2[2 * kk + 1];
      }
    }
  }
  a0 += __shfl_xor(a0, 1, 64); a0 += __shfl_xor(a0, 2, 64);
  a1 += __shfl_xor(a1, 1, 64); a1 += __shfl_xor(a1, 2, 64);
  a2 += __shfl_xor(a2, 1, 64); a2 += __shfl_xor(a2, 2, 64);
  if (ch4 < 3) {
    const float av = ch4 == 0 ? a0 : (ch4 == 1 ? a1 : a2);
    const int oy = 2 * jj + (1 - py), ox = 2 * ii + (1 - px);
    const float t = av + b2f(bias[ch4]);
    xhat[(((size_t)(chunkBase + b) * 3 + ch4) * 256 + oy) * 256 + ox] =
        1.0f / (1.0f + expf(-t));
  }
}

// =====================================================================
extern "C" void kernel_launch(void* const* d_in, const int* in_sizes, int n_in,
                              void* d_out, int out_size, void* d_ws, size_t ws_size,
                              hipStream_t stream)
{
  float* xhat = (float*)d_out;
  float* lossout = xhat + (out_size - 1);

  const size_t NEED = 130195456;
  if (ws_size < NEED) return;

  char* ws = (char*)d_ws;
  int*   flag  = (int*)  (ws + 0);
  float* lsum  = (float*)(ws + 1024);
  int*   idx   = (int*)  (ws + 65536);
  u64*   ku    = (u64*)  (ws + 131072);
  bf16*  P     = (bf16*) (ws + 8519680);
  bf16*  WT    = (bf16*) (ws + 27262976);
  float* cnorm = (float*)(ws + 30900224);
  bf16*  hbuf  = (bf16*) (ws + 31457280);
  bf16*  A_im  = (bf16*) (ws + 35651584);
  bf16*  ffb   = (bf16*) (ws + 52428800);
  bf16*  Pfb   = (bf16*) (ws + 85983232);
  bf16*  a0    = (bf16*) (ws + 35651584);
  bf16*  a1    = (bf16*) (ws + 40960000);
  bf16*  a2    = (bf16*) (ws + 59899904);
  bf16*  a3    = (bf16*) (ws + 95584256);

  k_detect<<<1, 64, 0, stream>>>((const u32*)d_in[7], flag);

  size_t poff[26]; poff[1] = 0;
  for (int i = 2; i <= 25; ++i) poff[i] = poff[i - 1] + (size_t)in_sizes[i - 1];
  const size_t ptotal = poff[25] + (size_t)in_sizes[25];
  PPack pp;
  for (int i = 0; i < 25; ++i) { pp.s[i] = d_in[i + 1]; pp.off[i] = (u32)poff[i + 1]; }
  pp.off[25] = (u32)ptotal;
  k_convall<<<(int)((ptotal + 255) / 256), 256, 0, stream>>>(pp, P, flag);

  const bf16 *patch_w = P + poff[1],  *patch_b = P + poff[2];
  const bf16 *qkv_w   = P + poff[3],  *qkv_b   = P + poff[4];
  const bf16 *out_w   = P + poff[5],  *out_b   = P + poff[6];
  const bf16 *ln1_w   = P + poff[7],  *ln1_b   = P + poff[8];
  const bf16 *ln2_w   = P + poff[9],  *ln2_b   = P + poff[10];
  const bf16 *ff1_w   = P + poff[11], *ff1_b   = P + poff[12];
  const bf16 *ff2_w   = P + poff[13], *ff2_b   = P + poff[14];
  const bf16 *lnf_w   = P + poff[15], *lnf_b   = P + poff[16];
  const bf16 *codebook= P + poff[17];
  const bf16 *dec_w0  = P + poff[18], *dec_b0  = P + poff[19];
  const bf16 *dec_w1  = P + poff[20], *dec_b1  = P + poff[21];
  const bf16 *dec_w2  = P + poff[22], *dec_b2  = P + poff[23];
  const bf16 *dec_w3  = P + poff[24], *dec_b3  = P + poff[25];

  bf16* wt0 = WT;
  bf16* wt1 = wt0 + 1048576;
  bf16* wt2 = wt1 + 524288;
  bf16* wt3 = wt2 + 131072;
  k_wtrans<<<(1048576 + 255) / 256, 256, 0, stream>>>(dec_w0, wt0, 256, 8, 256, 256);
  k_wtrans<<<(524288 + 255) / 256, 256, 0, stream>>>(dec_w1, wt1, 256, 8, 128, 128);
  k_wtrans<<<(131072 + 255) / 256, 256, 0, stream>>>(dec_w2, wt2, 128, 7, 64, 64);
  k_wtrans<<<(3072 + 255) / 256, 256, 0, stream>>>(dec_w3, wt3, 64, 6, 3, 3);
  k_cnorm<<<32, 256, 0, stream>>>(codebook, cnorm);

  // patch embedding: split-K (4 x Kc=768, dbuf) -> bf16 partials + reduce+bias
  k_im2col<<<dim3(3, 8192), 128, 0, stream>>>(d_in[0], A_im, flag);
  gemm_t<4, 2, 128, true><<<dim3(2, 128, 4), 256, 0, stream>>>(
      A_im, patch_w, nullptr, nullptr, Pfb, nullptr, nullptr, 8192, 256, 3072, 768);
  k_lnred<false><<<8192, 256, 0, stream>>>(
      Pfb, patch_b, nullptr, nullptr, nullptr, nullptr, nullptr, hbuf, 4);

  // transformer encoder: fused attention block + FF path (ff2 split-K depth 2);
  // layer 5's lnred additionally applies lnf
  for (int l = 0; l < 6; ++l) {
    k_fat1<<<256, 256, 0, stream>>>(
        hbuf, qkv_w + (size_t)l * 768 * 256, qkv_b + l * 768,
        out_w + (size_t)l * 256 * 256, out_b + l * 256,
        ln1_w + l * 256, ln1_b + l * 256);
    gemm_t<1, 2, 256, false><<<dim3(4, 128, 1), 256, 0, stream>>>(
        hbuf, ff1_w + (size_t)l * 1024 * 256, ff1_b + l * 1024, nullptr, ffb,
        nullptr, nullptr, 8192, 1024, 256, 256);
    gemm_t<4, 2, 128, false><<<dim3(2, 128, 2), 256, 0, stream>>>(
        ffb, ff2_w + (size_t)l * 256 * 1024, nullptr, nullptr, Pfb,
        nullptr, nullptr, 8192, 256, 1024, 512);
    k_lnred<true><<<8192, 256, 0, stream>>>(
        Pfb, ff2_b + l * 256, hbuf, ln2_w + l * 256, ln2_b + l * 256,
        (l == 5) ? lnf_w : nullptr, (l == 5) ? lnf_b : nullptr, hbuf, 2);
  }

  // VQ via MFMA + packed-key argmin (proven FM=2 x BN=256 config)
  gemm_t<3, 2, 256, false><<<dim3(32, 128, 1), 256, 0, stream>>>(
      hbuf, codebook, nullptr, nullptr, nullptr, cnorm, ku, 8192, 8192, 256, 256);
  k_vqmerge<<<32, 256, 0, stream>>>(ku, idx, 8192, 32);

  k_zborder<<<(32 * 68 * 32 + 255) / 256, 256, 0, stream>>>(a0, 18, 256, 32);
  k_gather<<<8192, 256, 0, stream>>>(hbuf, codebook, idx, a0, lsum);
  k_loss<<<1, 256, 0, stream>>>(lsum, lossout);
  k_zborder<<<(32 * 132 * 32 + 255) / 256, 256, 0, stream>>>(a1, 34, 256, 32);
  k_zborder<<<(32 * 260 * 16 + 255) / 256, 256, 0, stream>>>(a2, 66, 128, 32);
  k_zborder<<<(16 * 516 * 8 + 255) / 256, 256, 0, stream>>>(a3, 130, 64, 16);

  // decoder
  convt64<<<dim3(4, 64, 4), 256, 0, stream>>>(a0, wt0, dec_b0, a1, 16, 4, 256, 8, 256);
  convt64<<<dim3(2, 256, 4), 256, 0, stream>>>(a1, wt1, dec_b1, a2, 32, 5, 256, 8, 128);
  for (int c = 0; c < 2; ++c) {
    const bf16* a2c = a2 + (size_t)c * 16 * 66 * 66 * 128;
    convt64<<<dim3(1, 512, 4), 256, 0, stream>>>(a2c, wt2, dec_b2, a3, 64, 6, 128, 7, 64);
    k_dec3<<<dim3(256, 4, 16), 256, 0, stream>>>(a3, wt3, dec_b3, xhat, c * 16);
  }
}

// Round 27
// 957.963 us; speedup vs baseline: 1.0090x; 1.0028x over previous
//
#include <hip/hip_runtime.h>
#include <hip/hip_bf16.h>
#include <math.h>

typedef __hip_bfloat16 bf16;
typedef unsigned int u32;
typedef unsigned long long u64;
using short8 = __attribute__((ext_vector_type(8))) short;
using f32x4  = __attribute__((ext_vector_type(4))) float;

__device__ __forceinline__ float b2f(bf16 v){ return __bfloat162float(v); }
__device__ __forceinline__ bf16  f2b(float v){ return __float2bfloat16(v); }
__device__ __forceinline__ float plo(u32 u){ return __uint_as_float(u << 16); }
__device__ __forceinline__ float phi(u32 u){ return __uint_as_float(u & 0xffff0000u); }

__device__ __forceinline__ void gld16(const void* g, void* l)
{
  __builtin_amdgcn_global_load_lds(
      (const __attribute__((address_space(1))) u32*)g,
      (__attribute__((address_space(3))) u32*)l, 16, 0, 0);
}

// ---- dtype probe ----
__global__ void k_detect(const u32* probe, int* flag)
{
  if (threadIdx.x == 0 && blockIdx.x == 0)
    *flag = (*probe == 0x3F800000u) ? 0 : 1;
}

// ---- all param arrays -> canonical bf16, one dispatch ----
struct PPack { const void* s[25]; u32 off[26]; };
__global__ __launch_bounds__(256) void k_convall(PPack pp, bf16* P, const int* flag)
{
  const u32 i = blockIdx.x * 256 + threadIdx.x;
  if (i >= pp.off[25]) return;
  int lo = 0, hi = 25;
  while (hi - lo > 1) { const int mid = (lo + hi) >> 1; if (i >= pp.off[mid]) lo = mid; else hi = mid; }
  const u32 j = i - pp.off[lo];
  P[i] = *flag ? ((const bf16*)pp.s[lo])[j] : f2b(((const float*)pp.s[lo])[j]);
}

// ---- zero only the 1-pixel border ring of a padded channels-last buffer ----
__global__ __launch_bounds__(256) void k_zborder(bf16* buf, int Hp, int C, int nimg)
{
  const int per = 4 * Hp - 4;
  const int c8 = C >> 3;
  const int total = nimg * per * c8;
  const int i = blockIdx.x * 256 + threadIdx.x;
  if (i >= total) return;
  const int ch8 = i % c8;
  const int pb = i / c8;
  const int img = pb / per;
  const int b = pb - img * per;
  int y, x;
  if (b < Hp) { y = 0; x = b; }
  else if (b < 2 * Hp) { y = Hp - 1; x = b - Hp; }
  else {
    const int r = b - 2 * Hp;
    const int side = r / (Hp - 2);
    y = 1 + r - side * (Hp - 2);
    x = side ? (Hp - 1) : 0;
  }
  uint4 z = {0, 0, 0, 0};
  *reinterpret_cast<uint4*>(buf + (((size_t)img * Hp + y) * Hp + x) * C + ch8 * 8) = z;
}

// ---- vectorized im2col: x (f32 or bf16) -> A_im bf16 (8192 x 3072) ----
__global__ __launch_bounds__(128) void k_im2col(const void* x, bf16* A, const int* flag)
{
  const int m = blockIdx.y;
  const int k8 = blockIdx.x * 128 + threadIdx.x;
  const int k = k8 * 8;
  const int b = m >> 8, n = m & 255;
  const int gy = n >> 4, gx = n & 15;
  const int c = k >> 10, r = (k >> 5) & 31, pp = k & 31;
  const size_t src = (((size_t)(b * 3 + c) * 512) + gy * 32 + r) * 512 + gx * 32 + pp;
  bf16 ov[8];
  if (*flag) {
    const bf16* xp = (const bf16*)x + src;
    #pragma unroll
    for (int i = 0; i < 8; ++i) ov[i] = xp[i];
  } else {
    const float4 v0 = *reinterpret_cast<const float4*>((const float*)x + src);
    const float4 v1 = *reinterpret_cast<const float4*>((const float*)x + src + 4);
    ov[0]=f2b(v0.x); ov[1]=f2b(v0.y); ov[2]=f2b(v0.z); ov[3]=f2b(v0.w);
    ov[4]=f2b(v1.x); ov[5]=f2b(v1.y); ov[6]=f2b(v1.z); ov[7]=f2b(v1.w);
  }
  *reinterpret_cast<uint4*>(A + (size_t)m * 3072 + k) = *reinterpret_cast<const uint4*>(ov);
}

// === MFMA GEMM, BM=FM*32, BN in {128,256}; optional dbuf; split-K via grid.z ===
template<int EPI, int FM, int BN, bool DB>
__global__ __launch_bounds__(256, 2) void gemm_t(
    const bf16* __restrict__ A, const bf16* __restrict__ Bw,
    const bf16* __restrict__ bias, const bf16* res, bf16* C,
    const float* __restrict__ cnorm, u64* __restrict__ ku,
    int M, int N, int K, int Kc)
{
  constexpr int BM = FM * 32;
  constexpr int FN = BN / 32;
  __shared__ alignas(16) bf16 As[DB ? 2 : 1][BM * 64];
  __shared__ alignas(16) bf16 Bs[DB ? 2 : 1][BN * 64];
  const int tid = threadIdx.x;
  const int bn = blockIdx.x * BN, bm = blockIdx.y * BM;
  const int z = blockIdx.z;
  const int kb = z * Kc;
  const int l = tid & 63, w = tid >> 6;
  const int wm = w >> 1, wn = w & 1;
  const int lg = l >> 4, lr = l & 15;
  const int sr8 = l >> 3;
  const int sch = (l & 7) ^ sr8;
  f32x4 acc[FM][FN];
  #pragma unroll
  for (int fm = 0; fm < FM; ++fm)
    #pragma unroll
    for (int fn = 0; fn < FN; ++fn) acc[fm][fn] = (f32x4){0.f, 0.f, 0.f, 0.f};

  auto stage = [&](int bb, int k0) {
    char* ab = (char*)As[bb];
    char* bp = (char*)Bs[bb];
    #pragma unroll
    for (int it = 0; it < FM; ++it) {
      const int r = w * 8 + it * 32 + sr8;
      gld16(A + (size_t)(bm + r) * K + k0 + sch * 8, ab + w * 1024 + it * 4096);
    }
    #pragma unroll
    for (int it = 0; it < BN / 32; ++it) {
      const int r = w * 8 + it * 32 + sr8;
      gld16(Bw + (size_t)(bn + r) * K + k0 + sch * 8, bp + w * 1024 + it * 4096);
    }
  };
  auto compute = [&](int bb) {
    const char* ab = (const char*)As[bb];
    const char* bp = (const char*)Bs[bb];
    #pragma unroll
    for (int ks = 0; ks < 2; ++ks) {
      short8 af[FM], bfr[FN];
      #pragma unroll
      for (int fm = 0; fm < FM; ++fm) {
        const int r = wm * (FM * 16) + fm * 16 + lr;
        af[fm] = *reinterpret_cast<const short8*>(ab + r * 128 + (((lg + ks * 4) ^ (r & 7)) * 16));
      }
      #pragma unroll
      for (int fn = 0; fn < FN; ++fn) {
        const int r = wn * (BN / 2) + fn * 16 + lr;
        bfr[fn] = *reinterpret_cast<const short8*>(bp + r * 128 + (((lg + ks * 4) ^ (r & 7)) * 16));
      }
      #pragma unroll
      for (int fm = 0; fm < FM; ++fm)
        #pragma unroll
        for (int fn = 0; fn < FN; ++fn)
          acc[fm][fn] = __builtin_amdgcn_mfma_f32_16x16x32_bf16(af[fm], bfr[fn], acc[fm][fn], 0, 0, 0);
    }
  };

  const int nt = Kc >> 6;
  if (DB) {
    stage(0, kb);
    __syncthreads();
    for (int t = 0; t < nt; ++t) {
      const int cur = t & 1;
      if (t + 1 < nt) stage(cur ^ 1, kb + ((t + 1) << 6));
      compute(cur);
      __syncthreads();
    }
  } else {
    for (int t = 0; t < nt; ++t) {
      if (t) __syncthreads();
      stage(0, kb + (t << 6));
      __syncthreads();
      compute(0);
    }
  }

  if (EPI == 3) {
    __shared__ u64 skey[BM][2];
    float cn[FN];
    #pragma unroll
    for (int fn = 0; fn < FN; ++fn) cn[fn] = cnorm[bn + wn * (BN / 2) + fn * 16 + lr];
    #pragma unroll
    for (int fm = 0; fm < FM; ++fm) {
      #pragma unroll
      for (int r = 0; r < 4; ++r) {
        u64 best = ~0ull;
        #pragma unroll
        for (int fn = 0; fn < FN; ++fn) {
          const int col = bn + wn * (BN / 2) + fn * 16 + lr;
          const float d = cn[fn] - 2.0f * acc[fm][fn][r];
          u32 u = __float_as_uint(d);
          u = (u & 0x80000000u) ? ~u : (u | 0x80000000u);
          const u64 key = ((u64)u << 32) | (u32)col;
          best = key < best ? key : best;
        }
        #pragma unroll
        for (int mk = 1; mk < 16; mk <<= 1) {
          const u64 o = __shfl_xor(best, mk, 64);
          best = o < best ? o : best;
        }
        if (lr == 0) skey[wm * (FM * 16) + fm * 16 + lg * 4 + r][wn] = best;
      }
    }
    __syncthreads();
    if (tid < BM) {
      const u64 a = skey[tid][0], b = skey[tid][1];
      ku[(size_t)blockIdx.x * M + bm + tid] = a < b ? a : b;
    }
  } else if (EPI == 4) {
    #pragma unroll
    for (int fm = 0; fm < FM; ++fm) {
      const int m0 = bm + wm * (FM * 16) + fm * 16 + lg * 4;
      #pragma unroll
      for (int fn = 0; fn < FN; ++fn) {
        const int n = bn + wn * (BN / 2) + fn * 16 + lr;
        #pragma unroll
        for (int r = 0; r < 4; ++r)
          C[((size_t)z * M + m0 + r) * N + n] = f2b(acc[fm][fn][r]);
      }
    }
  } else {
    #pragma unroll
    for (int fm = 0; fm < FM; ++fm) {
      const int m0 = bm + wm * (FM * 16) + fm * 16 + lg * 4;
      #pragma unroll
      for (int fn = 0; fn < FN; ++fn) {
        const int n = bn + wn * (BN / 2) + fn * 16 + lr;
        const float bs = b2f(bias[n]);
        #pragma unroll
        for (int r = 0; r < 4; ++r) {
          float v = acc[fm][fn][r] + bs;
          if (EPI == 1) v = 0.5f * v * (1.0f + erff(v * 0.70710678118654752f));
          if (EPI == 2) v += b2f(res[(size_t)(m0 + r) * N + n]);
          C[(size_t)(m0 + r) * N + n] = f2b(v);
        }
      }
    }
  }
}

// ====== fused per-bt transformer phase 1: qkv -> attention -> attnout+res+LN1 ======
__global__ __launch_bounds__(256, 1) void k_fat1(
    bf16* __restrict__ hbuf,
    const bf16* __restrict__ Wqkv, const bf16* __restrict__ Bqkv,
    const bf16* __restrict__ Wo, const bf16* __restrict__ Bo,
    const bf16* __restrict__ lw, const bf16* __restrict__ lb)
{
  __shared__ alignas(16) bf16 hs[32 * 256];
  __shared__ alignas(16) bf16 ao[32 * 256];
  __shared__ alignas(16) bf16 astage[128 * 64];
  __shared__ bf16 att[3 * 9216];
  __shared__ float ps[32][33];
  __shared__ float rs[32];
  __shared__ float psum[32][4], psq[32][4];
  __shared__ float mstat[32], istat[32];

  const int bt = blockIdx.x;
  const int tid = threadIdx.x;
  const int l = tid & 63, w = tid >> 6;
  const int lg = l >> 4, lr = l & 15;
  const int sr8 = l >> 3;
  const int sch = (l & 7) ^ sr8;
  char* hsb = (char*)hs;
  char* aob = (char*)ao;
  char* asb = (char*)astage;

  #pragma unroll
  for (int call = 0; call < 4; ++call) {
    const int id = call * 256 + tid;
    const int s = id >> 5, within = id & 31;
    const int grp = within >> 3, c = within & 7;
    gld16(hbuf + (size_t)(s * 256 + bt) * 256 + grp * 64 + ((c ^ (s & 7)) * 8),
          hsb + call * 4096 + w * 1024);
  }

  for (int at = 0; at < 6; ++at) {
    f32x4 acc[2][2];
    #pragma unroll
    for (int fm = 0; fm < 2; ++fm)
      #pragma unroll
      for (int fn = 0; fn < 2; ++fn) acc[fm][fn] = (f32x4){0.f, 0.f, 0.f, 0.f};
    for (int kst = 0; kst < 4; ++kst) {
      __syncthreads();
      #pragma unroll
      for (int it = 0; it < 4; ++it) {
        const int r = w * 8 + it * 32 + sr8;
        gld16(Wqkv + (size_t)(at * 128 + r) * 256 + kst * 64 + sch * 8,
              asb + w * 1024 + it * 4096);
      }
      __syncthreads();
      #pragma unroll
      for (int ks = 0; ks < 2; ++ks) {
        short8 af[2], bfr[2];
        #pragma unroll
        for (int fm = 0; fm < 2; ++fm) {
          const int r = w * 32 + fm * 16 + lr;
          af[fm] = *reinterpret_cast<const short8*>(asb + r * 128 + (((lg + ks * 4) ^ (r & 7)) * 16));
        }
        #pragma unroll
        for (int fn = 0; fn < 2; ++fn) {
          const int sr = fn * 16 + lr;
          bfr[fn] = *reinterpret_cast<const short8*>(hsb + sr * 512 + kst * 128 + (((lg + ks * 4) ^ (sr & 7)) * 16));
        }
        #pragma unroll
        for (int fm = 0; fm < 2; ++fm)
          #pragma unroll
          for (int fn = 0; fn < 2; ++fn)
            acc[fm][fn] = __builtin_amdgcn_mfma_f32_16x16x32_bf16(af[fm], bfr[fn], acc[fm][fn], 0, 0, 0);
      }
    }
    #pragma unroll
    for (int fm = 0; fm < 2; ++fm) {
      #pragma unroll
      for (int fn = 0; fn < 2; ++fn) {
        const int s = fn * 16 + lr;
        #pragma unroll
        for (int r = 0; r < 4; ++r) {
          const int n = at * 128 + w * 32 + fm * 16 + lg * 4 + r;
          const int p = n >> 8, rem = n & 255;
          att[p * 9216 + (rem >> 5) * 1152 + s * 36 + (rem & 31)] =
              f2b(acc[fm][fn][r] + b2f(Bqkv[n]));
        }
      }
    }
  }
  __syncthreads();

  const int s_a = tid >> 3, j_a = tid & 7;
  for (int hd = 0; hd < 8; ++hd) {
    const bf16* qrow = att + hd * 1152 + s_a * 36;
    float sc[4];
    #pragma unroll
    for (int e = 0; e < 4; ++e) {
      const int t = j_a + 8 * e;
      const bf16* krow = att + 9216 + hd * 1152 + t * 36;
      float v = 0.f;
      #pragma unroll
      for (int dd = 0; dd < 32; ++dd) v += b2f(qrow[dd]) * b2f(krow[dd]);
      sc[e] = v * 0.17677669529663687f;
    }
    float mx = fmaxf(fmaxf(sc[0], sc[1]), fmaxf(sc[2], sc[3]));
    #pragma unroll
    for (int mk = 1; mk < 8; mk <<= 1) mx = fmaxf(mx, __shfl_xor(mx, mk, 64));
    float sm = 0.f; float ex[4];
    #pragma unroll
    for (int e = 0; e < 4; ++e) { ex[e] = expf(sc[e] - mx); sm += ex[e]; }
    #pragma unroll
    for (int mk = 1; mk < 8; mk <<= 1) sm += __shfl_xor(sm, mk, 64);
    #pragma unroll
    for (int e = 0; e < 4; ++e) ps[s_a][j_a + 8 * e] = ex[e];
    if (j_a == 0) rs[s_a] = 1.0f / sm;
    __syncthreads();
    const float rinv = rs[s_a];
    float av[4];
    #pragma unroll
    for (int e = 0; e < 4; ++e) {
      const int dd = j_a * 4 + e;
      float a = 0.f;
      #pragma unroll
      for (int t = 0; t < 32; ++t)
        a += ps[s_a][t] * b2f(att[2 * 9216 + hd * 1152 + t * 36 + dd]);
      av[e] = a * rinv;
    }
    alignas(8) bf16 ov[4];
    #pragma unroll
    for (int e = 0; e < 4; ++e) ov[e] = f2b(av[e]);
    const int clog = (hd & 1) * 4 + (j_a >> 1);
    *reinterpret_cast<ushort4*>(aob + s_a * 512 + (hd >> 1) * 128 +
        ((clog ^ (s_a & 7)) * 16) + (j_a & 1) * 8) =
        *reinterpret_cast<const ushort4*>(ov);
    __syncthreads();
  }

  float vals[2][2][2][4];
  for (int at = 0; at < 2; ++at) {
    f32x4 acc[2][2];
    #pragma unroll
    for (int fm = 0; fm < 2; ++fm)
      #pragma unroll
      for (int fn = 0; fn < 2; ++fn) acc[fm][fn] = (f32x4){0.f, 0.f, 0.f, 0.f};
    for (int kst = 0; kst < 4; ++kst) {
      __syncthreads();
      #pragma unroll
      for (int it = 0; it < 4; ++it) {
        const int r = w * 8 + it * 32 + sr8;
        gld16(Wo + (size_t)(at * 128 + r) * 256 + kst * 64 + sch * 8,
              asb + w * 1024 + it * 4096);
      }
      __syncthreads();
      #pragma unroll
      for (int ks = 0; ks < 2; ++ks) {
        short8 af[2], bfr[2];
        #pragma unroll
        for (int fm = 0; fm < 2; ++fm) {
          const int r = w * 32 + fm * 16 + lr;
          af[fm] = *reinterpret_cast<const short8*>(asb + r * 128 + (((lg + ks * 4) ^ (r & 7)) * 16));
        }
        #pragma unroll
        for (int fn = 0; fn < 2; ++fn) {
          const int sr = fn * 16 + lr;
          bfr[fn] = *reinterpret_cast<const short8*>(aob + sr * 512 + kst * 128 + (((lg + ks * 4) ^ (sr & 7)) * 16));
        }
        #pragma unroll
        for (int fm = 0; fm < 2; ++fm)
          #pragma unroll
          for (int fn = 0; fn < 2; ++fn)
            acc[fm][fn] = __builtin_amdgcn_mfma_f32_16x16x32_bf16(af[fm], bfr[fn], acc[fm][fn], 0, 0, 0);
      }
    }
    #pragma unroll
    for (int fm = 0; fm < 2; ++fm)
      #pragma unroll
      for (int fn = 0; fn < 2; ++fn)
        #pragma unroll
        for (int r = 0; r < 4; ++r) vals[at][fm][fn][r] = acc[fm][fn][r];
  }

  float s1[2] = {0.f, 0.f}, s2[2] = {0.f, 0.f};
  #pragma unroll
  for (int at = 0; at < 2; ++at) {
    #pragma unroll
    for (int fm = 0; fm < 2; ++fm) {
      const int n4 = at * 128 + w * 32 + fm * 16 + lg * 4;
      #pragma unroll
      for (int fn = 0; fn < 2; ++fn) {
        const int s = fn * 16 + lr;
        const ushort4 hr = *reinterpret_cast<const ushort4*>(
            hsb + s * 512 + (n4 >> 6) * 128 + ((((n4 >> 3) & 7) ^ (s & 7)) * 16) + (n4 & 7) * 2);
        const bf16* hb = reinterpret_cast<const bf16*>(&hr);
        #pragma unroll
        for (int r = 0; r < 4; ++r) {
          const float v = vals[at][fm][fn][r] + b2f(Bo[n4 + r]) + b2f(hb[r]);
          vals[at][fm][fn][r] = v;
          s1[fn] += v;
          s2[fn] += v * v;
        }
      }
    }
  }
  #pragma unroll
  for (int fn = 0; fn < 2; ++fn) {
    float a = s1[fn], b = s2[fn];
    a += __shfl_xor(a, 16, 64); a += __shfl_xor(a, 32, 64);
    b += __shfl_xor(b, 16, 64); b += __shfl_xor(b, 32, 64);
    if (lg == 0) { psum[fn * 16 + lr][w] = a; psq[fn * 16 + lr][w] = b; }
  }
  __syncthreads();
  if (tid < 32) {
    float sa = 0.f, sb = 0.f;
    #pragma unroll
    for (int k = 0; k < 4; ++k) { sa += psum[tid][k]; sb += psq[tid][k]; }
    const float m = sa * (1.0f / 256.0f);
    mstat[tid] = m;
    istat[tid] = 1.0f / sqrtf(sb * (1.0f / 256.0f) - m * m + 1e-5f);
  }
  __syncthreads();
  #pragma unroll
  for (int at = 0; at < 2; ++at) {
    #pragma unroll
    for (int fm = 0; fm < 2; ++fm) {
      const int n4 = at * 128 + w * 32 + fm * 16 + lg * 4;
      #pragma unroll
      for (int fn = 0; fn < 2; ++fn) {
        const int s = fn * 16 + lr;
        const float m = mstat[s], inv = istat[s];
        alignas(8) bf16 ov[4];
        #pragma unroll
        for (int r = 0; r < 4; ++r)
          ov[r] = f2b((vals[at][fm][fn][r] - m) * inv * b2f(lw[n4 + r]) + b2f(lb[n4 + r]));
        *reinterpret_cast<ushort4*>(hbuf + (size_t)(s * 256 + bt) * 256 + n4) =
            *reinterpret_cast<const ushort4*>(ov);
      }
    }
  }
}

// ---- split-K reduce (bf16 partials) + bias (+res) + LN (+optional 2nd LN) ----
// wave-shfl (sum, sumsq) reduce + 4-word LDS combine: 2-3 barriers vs 18-tree
template<bool DOLN>
__global__ __launch_bounds__(256) void k_lnred(
    const bf16* __restrict__ Pf, const bf16* __restrict__ bias,
    const bf16* res, const bf16* __restrict__ lw, const bf16* __restrict__ lb,
    const bf16* lw2, const bf16* lb2,
    bf16* h, int kc)
{
  __shared__ float wsum[4], wsq[4];
  const int row = blockIdx.x, d = threadIdx.x;
  const int w = d >> 6;
  float s = 0.f;
  for (int z = 0; z < kc; ++z) s += b2f(Pf[((size_t)z * 8192 + row) * 256 + d]);
  s += b2f(bias[d]);
  if (res) s += b2f(res[(size_t)row * 256 + d]);
  if (!DOLN) { h[(size_t)row * 256 + d] = f2b(s); return; }
  float a = s, b = s * s;
  #pragma unroll
  for (int mk = 1; mk < 64; mk <<= 1) {
    a += __shfl_xor(a, mk, 64);
    b += __shfl_xor(b, mk, 64);
  }
  if ((d & 63) == 0) { wsum[w] = a; wsq[w] = b; }
  __syncthreads();
  float sa = wsum[0] + wsum[1] + wsum[2] + wsum[3];
  float sb = wsq[0] + wsq[1] + wsq[2] + wsq[3];
  float m = sa * (1.0f / 256.0f);
  float inv = 1.0f / sqrtf(sb * (1.0f / 256.0f) - m * m + 1e-5f);
  float y = (s - m) * inv * b2f(lw[d]) + b2f(lb[d]);
  if (lw2) {
    // fused second LayerNorm (lnf)
    __syncthreads();
    a = y; b = y * y;
    #pragma unroll
    for (int mk = 1; mk < 64; mk <<= 1) {
      a += __shfl_xor(a, mk, 64);
      b += __shfl_xor(b, mk, 64);
    }
    if ((d & 63) == 0) { wsum[w] = a; wsq[w] = b; }
    __syncthreads();
    sa = wsum[0] + wsum[1] + wsum[2] + wsum[3];
    sb = wsq[0] + wsq[1] + wsq[2] + wsq[3];
    m = sa * (1.0f / 256.0f);
    inv = 1.0f / sqrtf(sb * (1.0f / 256.0f) - m * m + 1e-5f);
    y = (y - m) * inv * b2f(lw2[d]) + b2f(lb2[d]);
  }
  h[(size_t)row * 256 + d] = f2b(y);
}

// ---- VQ merge over u64 keys (deterministic) ----
__global__ __launch_bounds__(256) void k_vqmerge(
    const u64* __restrict__ ku, int* __restrict__ idx, int M, int NB)
{
  const int r = blockIdx.x * 256 + threadIdx.x;
  if (r >= M) return;
  u64 best = ku[r];
  for (int nb = 1; nb < NB; ++nb) {
    const u64 k = ku[(size_t)nb * M + r];
    best = k < best ? k : best;
  }
  idx[r] = (int)(best & 0xFFFFFFFFull);
}

// ---- codebook norms ----
__global__ __launch_bounds__(256) void k_cnorm(const bf16* __restrict__ cb, float* __restrict__ cn)
{
  const int j = blockIdx.x * 256 + threadIdx.x;
  const u32* p = (const u32*)(cb + (size_t)j * 256);
  float s = 0.f;
  for (int k = 0; k < 128; ++k) {
    const u32 v = p[k];
    const float a = plo(v), b = phi(v);
    s += a * a + b * b;
  }
  cn[j] = s;
}

// ---- gather codebook -> padded channels-last a0 + per-row loss partials ----
// wave-shfl reduce + 4-word LDS combine (1 barrier vs 8-tree)
__global__ __launch_bounds__(256) void k_gather(
    const bf16* h, const bf16* cb, const int* idx, bf16* a0, float* lsum)
{
  __shared__ float ws[4];
  const int row = blockIdx.x, d = threadIdx.x;
  const int w = d >> 6;
  const int code = idx[row] & 8191;
  const float q = b2f(cb[(size_t)code * 256 + d]);
  const float x = b2f(h[(size_t)row * 256 + d]);
  float v = (q - x) * (q - x);
  #pragma unroll
  for (int mk = 1; mk < 64; mk <<= 1) v += __shfl_xor(v, mk, 64);
  if ((d & 63) == 0) ws[w] = v;
  __syncthreads();
  if (d == 0) lsum[row] = ws[0] + ws[1] + ws[2] + ws[3];
  const int b = row >> 8, n = row & 255;
  const int y = n >> 4, xc = n & 15;
  a0[(((size_t)b * 18 + y + 1) * 18 + (xc + 1)) * 256 + d] = f2b(q);
}

// ---- deterministic loss reduce -> f32 scalar ----
__global__ __launch_bounds__(256) void k_loss(const float* lsum, float* out)
{
  __shared__ float red[256];
  const int tid = threadIdx.x;
  float v = 0.f;
  for (int i = 0; i < 32; ++i) v += lsum[tid + 256 * i];
  red[tid] = v;
  __syncthreads();
  for (int off = 128; off > 0; off >>= 1) {
    if (tid < off) red[tid] += red[tid + off];
    __syncthreads();
  }
  if (tid == 0)
    out[0] = red[0] * (1.25f / 2097152.0f);
}

// ---- decoder weight transform ----
__global__ __launch_bounds__(256) void k_wtrans(
    const bf16* __restrict__ w, bf16* __restrict__ wt,
    int Cin, int lCin, int CoutR, int CoutP)
{
  const int K = Cin << 2;
  const int total = 4 * CoutP * K;
  const int i = blockIdx.x * 256 + threadIdx.x;
  if (i >= total) return;
  const int p = i / (CoutP * K);
  const int rem = i - p * (CoutP * K);
  const int co = rem / K;
  const int k = rem - co * K;
  const int tap = k >> lCin, ci = k - (tap << lCin);
  const int py = p >> 1, px = p & 1, ty = tap >> 1, tx = tap & 1;
  bf16 v = f2b(0.f);
  if (co < CoutR)
    v = w[(((size_t)ci * CoutR + co) * 4 + py + 2 * ty) * 4 + px + 2 * tx];
  wt[i] = v;
}

// ====== decoder convT implicit MFMA GEMM, double-buffered 2-phase ======
__global__ __launch_bounds__(256, 2) void convt64(
    const bf16* __restrict__ in, const bf16* __restrict__ Wt,
    const bf16* __restrict__ bias, bf16* __restrict__ outp,
    int H, int lH, int Cin, int lCin, int Cout)
{
  __shared__ alignas(16) bf16 As[2][128 * 64];
  __shared__ alignas(16) bf16 Bs[2][64 * 64];
  const int tid = threadIdx.x;
  const int pz = blockIdx.z;
  const int py = pz >> 1, px = pz & 1;
  const int K = Cin << 2;
  const int bn = blockIdx.x * 64, bm = blockIdx.y * 128;
  const bf16* Bw = Wt + (size_t)pz * Cout * K;
  const int l = tid & 63, w = tid >> 6;
  const int wm = w >> 1, wn = w & 1;
  const int lg = l >> 4, lr = l & 15;
  const int sr8 = l >> 3;
  const int sch = (l & 7) ^ sr8;
  const int Hp = H + 2;
  f32x4 acc[4][2];
  #pragma unroll
  for (int fm = 0; fm < 4; ++fm)
    #pragma unroll
    for (int fn = 0; fn < 2; ++fn) acc[fm][fn] = (f32x4){0.f, 0.f, 0.f, 0.f};

  size_t pixbase[4];
  #pragma unroll
  for (int it = 0; it < 4; ++it) {
    const int m = bm + w * 8 + it * 32 + sr8;
    const int b = m >> (2 * lH);
    const int rem = m & ((1 << (2 * lH)) - 1);
    const int jj = rem >> lH, ii = rem & (H - 1);
    pixbase[it] = ((size_t)(b * Hp + jj) * Hp + ii);
  }

  auto stage = [&](int bb, int k0) {
    char* ab = (char*)As[bb];
    char* bp = (char*)Bs[bb];
    const int tap = k0 >> lCin;
    const int ty = tap >> 1, tx = tap & 1;
    const int sy = (1 - py) + (1 - ty);
    const int sx = (1 - px) + (1 - tx);
    const int ci0 = (k0 - (tap << lCin)) + sch * 8;
    #pragma unroll
    for (int it = 0; it < 4; ++it)
      gld16(in + (pixbase[it] + (size_t)sy * Hp + sx) * Cin + ci0,
            ab + w * 1024 + it * 4096);
    #pragma unroll
    for (int it = 0; it < 2; ++it) {
      const int r = w * 8 + it * 32 + sr8;
      gld16(Bw + (size_t)(bn + r) * K + k0 + sch * 8, bp + w * 1024 + it * 4096);
    }
  };

  const int nt = K >> 6;
  stage(0, 0);
  __syncthreads();
  for (int t = 0; t < nt; ++t) {
    const int cur = t & 1;
    if (t + 1 < nt) stage(cur ^ 1, (t + 1) << 6);
    const char* ab = (const char*)As[cur];
    const char* bb = (const char*)Bs[cur];
    #pragma unroll
    for (int ks = 0; ks < 2; ++ks) {
      short8 af[4], bfr[2];
      #pragma unroll
      for (int fm = 0; fm < 4; ++fm) {
        const int r = wm * 64 + fm * 16 + lr;
        af[fm] = *reinterpret_cast<const short8*>(ab + r * 128 + (((lg + ks * 4) ^ (r & 7)) * 16));
      }
      #pragma unroll
      for (int fn = 0; fn < 2; ++fn) {
        const int r = wn * 32 + fn * 16 + lr;
        bfr[fn] = *reinterpret_cast<const short8*>(bb + r * 128 + (((lg + ks * 4) ^ (r & 7)) * 16));
      }
      #pragma unroll
      for (int fm = 0; fm < 4; ++fm)
        #pragma unroll
        for (int fn = 0; fn < 2; ++fn)
          acc[fm][fn] = __builtin_amdgcn_mfma_f32_16x16x32_bf16(af[fm], bfr[fn], acc[fm][fn], 0, 0, 0);
    }
    __syncthreads();
  }

  const int Ho = 2 * H, Hop = Ho + 2;
  #pragma unroll
  for (int fm = 0; fm < 4; ++fm) {
    const int m0 = bm + wm * 64 + fm * 16 + lg * 4;
    #pragma unroll
    for (int fn = 0; fn < 2; ++fn) {
      const int n = bn + wn * 32 + fn * 16 + lr;
      #pragma unroll
      for (int r = 0; r < 4; ++r) {
        const int m = m0 + r;
        const int b = m >> (2 * lH);
        const int rem = m & ((1 << (2 * lH)) - 1);
        const int jj = rem >> lH, ii = rem & (H - 1);
        const int oy = 2 * jj + (1 - py), ox = 2 * ii + (1 - px);
        const float v = fmaxf(acc[fm][fn][r] + b2f(bias[n]), 0.f);
        outp[((size_t)(b * Hop + oy + 1) * Hop + ox + 1) * Cout + n] = f2b(v);
      }
    }
  }
}

// ---- final decoder layer (Cout=3): coalesced vector kernel ----
__global__ __launch_bounds__(256) void k_dec3(
    const bf16* __restrict__ a3, const bf16* __restrict__ wt3,
    const bf16* __restrict__ bias, float* __restrict__ xhat, int chunkBase)
{
  __shared__ float wl[3][264];
  const int tid = threadIdx.x;
  const int pz = blockIdx.y;
  const int py = pz >> 1, px = pz & 1;
  for (int i = tid; i < 768; i += 256) {
    const int co = i >> 8, k = i & 255;
    wl[co][k] = b2f(wt3[(pz * 3 + co) * 256 + k]);
  }
  __syncthreads();
  const int b = blockIdx.z;
  const int p = blockIdx.x * 64 + (tid >> 2);
  const int jj = p >> 7, ii = p & 127;
  const int ch4 = tid & 3;
  float a0 = 0.f, a1 = 0.f, a2 = 0.f;
  #pragma unroll
  for (int ty = 0; ty < 2; ++ty) {
    #pragma unroll
    for (int tx = 0; tx < 2; ++tx) {
      const int sy = (1 - py) + (1 - ty), sx = (1 - px) + (1 - tx);
      const int tap = ty * 2 + tx;
      const u32* ip = (const u32*)(a3 + ((size_t)(b * 130 + jj + sy) * 130 + ii + sx) * 64) + ch4 * 8;
      const float* w0 = &wl[0][tap * 64 + ch4 * 16];
      const float* w1 = &wl[1][tap * 64 + ch4 * 16];
      const float* w2 = &wl[2][tap * 64 + ch4 * 16];
      #pragma unroll
      for (int kk = 0; kk < 8; ++kk) {
        const u32 v = ip[kk];
        const float e0 = plo(v), e1 = phi(v);
        a0 += e0 * w0[2 * kk] + e1 * w0[2 * kk + 1];
        a1 += e0 * w1[2 * kk] + e1 * w1[2 * kk + 1];
        a2 += e0 * w2[2 * kk] + e1 * w2[2 * kk + 1];
      }
    }
  }
  a0 += __shfl_xor(a0, 1, 64); a0 += __shfl_xor(a0, 2, 64);
  a1 += __shfl_xor(a1, 1, 64); a1 += __shfl_xor(a1, 2, 64);
  a2 += __shfl_xor(a2, 1, 64); a2 += __shfl_xor(a2, 2, 64);
  if (ch4 < 3) {
    const float av = ch4 == 0 ? a0 : (ch4 == 1 ? a1 : a2);
    const int oy = 2 * jj + (1 - py), ox = 2 * ii + (1 - px);
    const float t = av + b2f(bias[ch4]);
    xhat[(((size_t)(chunkBase + b) * 3 + ch4) * 256 + oy) * 256 + ox] =
        1.0f / (1.0f + expf(-t));
  }
}

// =====================================================================
extern "C" void kernel_launch(void* const* d_in, const int* in_sizes, int n_in,
                              void* d_out, int out_size, void* d_ws, size_t ws_size,
                              hipStream_t stream)
{
  float* xhat = (float*)d_out;
  float* lossout = xhat + (out_size - 1);

  const size_t NEED = 130195456;
  if (ws_size < NEED) return;

  char* ws = (char*)d_ws;
  int*   flag  = (int*)  (ws + 0);
  float* lsum  = (float*)(ws + 1024);
  int*   idx   = (int*)  (ws + 65536);
  u64*   ku    = (u64*)  (ws + 131072);
  bf16*  P     = (bf16*) (ws + 8519680);
  bf16*  WT    = (bf16*) (ws + 27262976);
  float* cnorm = (float*)(ws + 30900224);
  bf16*  hbuf  = (bf16*) (ws + 31457280);
  bf16*  A_im  = (bf16*) (ws + 35651584);
  bf16*  ffb   = (bf16*) (ws + 52428800);
  bf16*  Pfb   = (bf16*) (ws + 85983232);
  bf16*  a0    = (bf16*) (ws + 35651584);
  bf16*  a1    = (bf16*) (ws + 40960000);
  bf16*  a2    = (bf16*) (ws + 59899904);
  bf16*  a3    = (bf16*) (ws + 95584256);

  k_detect<<<1, 64, 0, stream>>>((const u32*)d_in[7], flag);

  size_t poff[26]; poff[1] = 0;
  for (int i = 2; i <= 25; ++i) poff[i] = poff[i - 1] + (size_t)in_sizes[i - 1];
  const size_t ptotal = poff[25] + (size_t)in_sizes[25];
  PPack pp;
  for (int i = 0; i < 25; ++i) { pp.s[i] = d_in[i + 1]; pp.off[i] = (u32)poff[i + 1]; }
  pp.off[25] = (u32)ptotal;
  k_convall<<<(int)((ptotal + 255) / 256), 256, 0, stream>>>(pp, P, flag);

  const bf16 *patch_w = P + poff[1],  *patch_b = P + poff[2];
  const bf16 *qkv_w   = P + poff[3],  *qkv_b   = P + poff[4];
  const bf16 *out_w   = P + poff[5],  *out_b   = P + poff[6];
  const bf16 *ln1_w   = P + poff[7],  *ln1_b   = P + poff[8];
  const bf16 *ln2_w   = P + poff[9],  *ln2_b   = P + poff[10];
  const bf16 *ff1_w   = P + poff[11], *ff1_b   = P + poff[12];
  const bf16 *ff2_w   = P + poff[13], *ff2_b   = P + poff[14];
  const bf16 *lnf_w   = P + poff[15], *lnf_b   = P + poff[16];
  const bf16 *codebook= P + poff[17];
  const bf16 *dec_w0  = P + poff[18], *dec_b0  = P + poff[19];
  const bf16 *dec_w1  = P + poff[20], *dec_b1  = P + poff[21];
  const bf16 *dec_w2  = P + poff[22], *dec_b2  = P + poff[23];
  const bf16 *dec_w3  = P + poff[24], *dec_b3  = P + poff[25];

  bf16* wt0 = WT;
  bf16* wt1 = wt0 + 1048576;
  bf16* wt2 = wt1 + 524288;
  bf16* wt3 = wt2 + 131072;
  k_wtrans<<<(1048576 + 255) / 256, 256, 0, stream>>>(dec_w0, wt0, 256, 8, 256, 256);
  k_wtrans<<<(524288 + 255) / 256, 256, 0, stream>>>(dec_w1, wt1, 256, 8, 128, 128);
  k_wtrans<<<(131072 + 255) / 256, 256, 0, stream>>>(dec_w2, wt2, 128, 7, 64, 64);
  k_wtrans<<<(3072 + 255) / 256, 256, 0, stream>>>(dec_w3, wt3, 64, 6, 3, 3);
  k_cnorm<<<32, 256, 0, stream>>>(codebook, cnorm);

  // patch embedding: split-K (4 x Kc=768, dbuf) -> bf16 partials + reduce+bias
  k_im2col<<<dim3(3, 8192), 128, 0, stream>>>(d_in[0], A_im, flag);
  gemm_t<4, 2, 128, true><<<dim3(2, 128, 4), 256, 0, stream>>>(
      A_im, patch_w, nullptr, nullptr, Pfb, nullptr, nullptr, 8192, 256, 3072, 768);
  k_lnred<false><<<8192, 256, 0, stream>>>(
      Pfb, patch_b, nullptr, nullptr, nullptr, nullptr, nullptr, hbuf, 4);

  // transformer encoder: fused attention block + FF path (ff2 split-K depth 2);
  // layer 5's lnred additionally applies lnf
  for (int l = 0; l < 6; ++l) {
    k_fat1<<<256, 256, 0, stream>>>(
        hbuf, qkv_w + (size_t)l * 768 * 256, qkv_b + l * 768,
        out_w + (size_t)l * 256 * 256, out_b + l * 256,
        ln1_w + l * 256, ln1_b + l * 256);
    gemm_t<1, 2, 256, false><<<dim3(4, 128, 1), 256, 0, stream>>>(
        hbuf, ff1_w + (size_t)l * 1024 * 256, ff1_b + l * 1024, nullptr, ffb,
        nullptr, nullptr, 8192, 1024, 256, 256);
    gemm_t<4, 2, 128, false><<<dim3(2, 128, 2), 256, 0, stream>>>(
        ffb, ff2_w + (size_t)l * 256 * 1024, nullptr, nullptr, Pfb,
        nullptr, nullptr, 8192, 256, 1024, 512);
    k_lnred<true><<<8192, 256, 0, stream>>>(
        Pfb, ff2_b + l * 256, hbuf, ln2_w + l * 256, ln2_b + l * 256,
        (l == 5) ? lnf_w : nullptr, (l == 5) ? lnf_b : nullptr, hbuf, 2);
  }

  // VQ via MFMA + packed-key argmin (proven FM=2 x BN=256 config)
  gemm_t<3, 2, 256, false><<<dim3(32, 128, 1), 256, 0, stream>>>(
      hbuf, codebook, nullptr, nullptr, nullptr, cnorm, ku, 8192, 8192, 256, 256);
  k_vqmerge<<<32, 256, 0, stream>>>(ku, idx, 8192, 32);

  k_zborder<<<(32 * 68 * 32 + 255) / 256, 256, 0, stream>>>(a0, 18, 256, 32);
  k_gather<<<8192, 256, 0, stream>>>(hbuf, codebook, idx, a0, lsum);
  k_loss<<<1, 256, 0, stream>>>(lsum, lossout);
  k_zborder<<<(32 * 132 * 32 + 255) / 256, 256, 0, stream>>>(a1, 34, 256, 32);
  k_zborder<<<(32 * 260 * 16 + 255) / 256, 256, 0, stream>>>(a2, 66, 128, 32);
  k_zborder<<<(16 * 516 * 8 + 255) / 256, 256, 0, stream>>>(a3, 130, 64, 16);

  // decoder
  convt64<<<dim3(4, 64, 4), 256, 0, stream>>>(a0, wt0, dec_b0, a1, 16, 4, 256, 8, 256);
  convt64<<<dim3(2, 256, 4), 256, 0, stream>>>(a1, wt1, dec_b1, a2, 32, 5, 256, 8, 128);
  for (int c = 0; c < 2; ++c) {
    const bf16* a2c = a2 + (size_t)c * 16 * 66 * 66 * 128;
    convt64<<<dim3(1, 512, 4), 256, 0, stream>>>(a2c, wt2, dec_b2, a3, 64, 6, 128, 7, 64);
    k_dec3<<<dim3(256, 4, 16), 256, 0, stream>>>(a3, wt3, dec_b3, xhat, c * 16);
  }
}

// Round 28
// 923.489 us; speedup vs baseline: 1.0467x; 1.0373x over previous
//
#include <hip/hip_runtime.h>
#include <hip/hip_bf16.h>
#include <math.h>

typedef __hip_bfloat16 bf16;
typedef unsigned int u32;
typedef unsigned long long u64;
using short8 = __attribute__((ext_vector_type(8))) short;
using f32x4  = __attribute__((ext_vector_type(4))) float;

__device__ __forceinline__ float b2f(bf16 v){ return __bfloat162float(v); }
__device__ __forceinline__ bf16  f2b(float v){ return __float2bfloat16(v); }
__device__ __forceinline__ float plo(u32 u){ return __uint_as_float(u << 16); }
__device__ __forceinline__ float phi(u32 u){ return __uint_as_float(u & 0xffff0000u); }

__device__ __forceinline__ void gld16(const void* g, void* l)
{
  __builtin_amdgcn_global_load_lds(
      (const __attribute__((address_space(1))) u32*)g,
      (__attribute__((address_space(3))) u32*)l, 16, 0, 0);
}

// ---- dtype probe ----
__global__ void k_detect(const u32* probe, int* flag)
{
  if (threadIdx.x == 0 && blockIdx.x == 0)
    *flag = (*probe == 0x3F800000u) ? 0 : 1;
}

// ---- all param arrays -> canonical bf16, one dispatch ----
struct PPack { const void* s[25]; u32 off[26]; };
__global__ __launch_bounds__(256) void k_convall(PPack pp, bf16* P, const int* flag)
{
  const u32 i = blockIdx.x * 256 + threadIdx.x;
  if (i >= pp.off[25]) return;
  int lo = 0, hi = 25;
  while (hi - lo > 1) { const int mid = (lo + hi) >> 1; if (i >= pp.off[mid]) lo = mid; else hi = mid; }
  const u32 j = i - pp.off[lo];
  P[i] = *flag ? ((const bf16*)pp.s[lo])[j] : f2b(((const float*)pp.s[lo])[j]);
}

// ---- zero only the 1-pixel border ring of a padded channels-last buffer ----
__global__ __launch_bounds__(256) void k_zborder(bf16* buf, int Hp, int C, int nimg)
{
  const int per = 4 * Hp - 4;
  const int c8 = C >> 3;
  const int total = nimg * per * c8;
  const int i = blockIdx.x * 256 + threadIdx.x;
  if (i >= total) return;
  const int ch8 = i % c8;
  const int pb = i / c8;
  const int img = pb / per;
  const int b = pb - img * per;
  int y, x;
  if (b < Hp) { y = 0; x = b; }
  else if (b < 2 * Hp) { y = Hp - 1; x = b - Hp; }
  else {
    const int r = b - 2 * Hp;
    const int side = r / (Hp - 2);
    y = 1 + r - side * (Hp - 2);
    x = side ? (Hp - 1) : 0;
  }
  uint4 z = {0, 0, 0, 0};
  *reinterpret_cast<uint4*>(buf + (((size_t)img * Hp + y) * Hp + x) * C + ch8 * 8) = z;
}

// ---- vectorized im2col: x (f32 or bf16) -> A_im bf16 (8192 x 3072) ----
__global__ __launch_bounds__(128) void k_im2col(const void* x, bf16* A, const int* flag)
{
  const int m = blockIdx.y;
  const int k8 = blockIdx.x * 128 + threadIdx.x;
  const int k = k8 * 8;
  const int b = m >> 8, n = m & 255;
  const int gy = n >> 4, gx = n & 15;
  const int c = k >> 10, r = (k >> 5) & 31, pp = k & 31;
  const size_t src = (((size_t)(b * 3 + c) * 512) + gy * 32 + r) * 512 + gx * 32 + pp;
  bf16 ov[8];
  if (*flag) {
    const bf16* xp = (const bf16*)x + src;
    #pragma unroll
    for (int i = 0; i < 8; ++i) ov[i] = xp[i];
  } else {
    const float4 v0 = *reinterpret_cast<const float4*>((const float*)x + src);
    const float4 v1 = *reinterpret_cast<const float4*>((const float*)x + src + 4);
    ov[0]=f2b(v0.x); ov[1]=f2b(v0.y); ov[2]=f2b(v0.z); ov[3]=f2b(v0.w);
    ov[4]=f2b(v1.x); ov[5]=f2b(v1.y); ov[6]=f2b(v1.z); ov[7]=f2b(v1.w);
  }
  *reinterpret_cast<uint4*>(A + (size_t)m * 3072 + k) = *reinterpret_cast<const uint4*>(ov);
}

// === MFMA GEMM, BM=FM*32, BN in {128,256}; optional dbuf; split-K via grid.z ===
template<int EPI, int FM, int BN, bool DB>
__global__ __launch_bounds__(256, 2) void gemm_t(
    const bf16* __restrict__ A, const bf16* __restrict__ Bw,
    const bf16* __restrict__ bias, const bf16* res, bf16* C,
    const float* __restrict__ cnorm, u64* __restrict__ ku,
    int M, int N, int K, int Kc)
{
  constexpr int BM = FM * 32;
  constexpr int FN = BN / 32;
  __shared__ alignas(16) bf16 As[DB ? 2 : 1][BM * 64];
  __shared__ alignas(16) bf16 Bs[DB ? 2 : 1][BN * 64];
  const int tid = threadIdx.x;
  const int bn = blockIdx.x * BN, bm = blockIdx.y * BM;
  const int z = blockIdx.z;
  const int kb = z * Kc;
  const int l = tid & 63, w = tid >> 6;
  const int wm = w >> 1, wn = w & 1;
  const int lg = l >> 4, lr = l & 15;
  const int sr8 = l >> 3;
  const int sch = (l & 7) ^ sr8;
  f32x4 acc[FM][FN];
  #pragma unroll
  for (int fm = 0; fm < FM; ++fm)
    #pragma unroll
    for (int fn = 0; fn < FN; ++fn) acc[fm][fn] = (f32x4){0.f, 0.f, 0.f, 0.f};

  auto stage = [&](int bb, int k0) {
    char* ab = (char*)As[bb];
    char* bp = (char*)Bs[bb];
    #pragma unroll
    for (int it = 0; it < FM; ++it) {
      const int r = w * 8 + it * 32 + sr8;
      gld16(A + (size_t)(bm + r) * K + k0 + sch * 8, ab + w * 1024 + it * 4096);
    }
    #pragma unroll
    for (int it = 0; it < BN / 32; ++it) {
      const int r = w * 8 + it * 32 + sr8;
      gld16(Bw + (size_t)(bn + r) * K + k0 + sch * 8, bp + w * 1024 + it * 4096);
    }
  };
  auto compute = [&](int bb) {
    const char* ab = (const char*)As[bb];
    const char* bp = (const char*)Bs[bb];
    #pragma unroll
    for (int ks = 0; ks < 2; ++ks) {
      short8 af[FM], bfr[FN];
      #pragma unroll
      for (int fm = 0; fm < FM; ++fm) {
        const int r = wm * (FM * 16) + fm * 16 + lr;
        af[fm] = *reinterpret_cast<const short8*>(ab + r * 128 + (((lg + ks * 4) ^ (r & 7)) * 16));
      }
      #pragma unroll
      for (int fn = 0; fn < FN; ++fn) {
        const int r = wn * (BN / 2) + fn * 16 + lr;
        bfr[fn] = *reinterpret_cast<const short8*>(bp + r * 128 + (((lg + ks * 4) ^ (r & 7)) * 16));
      }
      #pragma unroll
      for (int fm = 0; fm < FM; ++fm)
        #pragma unroll
        for (int fn = 0; fn < FN; ++fn)
          acc[fm][fn] = __builtin_amdgcn_mfma_f32_16x16x32_bf16(af[fm], bfr[fn], acc[fm][fn], 0, 0, 0);
    }
  };

  const int nt = Kc >> 6;
  if (DB) {
    stage(0, kb);
    __syncthreads();
    for (int t = 0; t < nt; ++t) {
      const int cur = t & 1;
      if (t + 1 < nt) stage(cur ^ 1, kb + ((t + 1) << 6));
      compute(cur);
      __syncthreads();
    }
  } else {
    for (int t = 0; t < nt; ++t) {
      if (t) __syncthreads();
      stage(0, kb + (t << 6));
      __syncthreads();
      compute(0);
    }
  }

  if (EPI == 3) {
    __shared__ u64 skey[BM][2];
    float cn[FN];
    #pragma unroll
    for (int fn = 0; fn < FN; ++fn) cn[fn] = cnorm[bn + wn * (BN / 2) + fn * 16 + lr];
    #pragma unroll
    for (int fm = 0; fm < FM; ++fm) {
      #pragma unroll
      for (int r = 0; r < 4; ++r) {
        u64 best = ~0ull;
        #pragma unroll
        for (int fn = 0; fn < FN; ++fn) {
          const int col = bn + wn * (BN / 2) + fn * 16 + lr;
          const float d = cn[fn] - 2.0f * acc[fm][fn][r];
          u32 u = __float_as_uint(d);
          u = (u & 0x80000000u) ? ~u : (u | 0x80000000u);
          const u64 key = ((u64)u << 32) | (u32)col;
          best = key < best ? key : best;
        }
        #pragma unroll
        for (int mk = 1; mk < 16; mk <<= 1) {
          const u64 o = __shfl_xor(best, mk, 64);
          best = o < best ? o : best;
        }
        if (lr == 0) skey[wm * (FM * 16) + fm * 16 + lg * 4 + r][wn] = best;
      }
    }
    __syncthreads();
    if (tid < BM) {
      const u64 a = skey[tid][0], b = skey[tid][1];
      ku[(size_t)blockIdx.x * M + bm + tid] = a < b ? a : b;
    }
  } else if (EPI == 4) {
    #pragma unroll
    for (int fm = 0; fm < FM; ++fm) {
      const int m0 = bm + wm * (FM * 16) + fm * 16 + lg * 4;
      #pragma unroll
      for (int fn = 0; fn < FN; ++fn) {
        const int n = bn + wn * (BN / 2) + fn * 16 + lr;
        #pragma unroll
        for (int r = 0; r < 4; ++r)
          C[((size_t)z * M + m0 + r) * N + n] = f2b(acc[fm][fn][r]);
      }
    }
  } else {
    #pragma unroll
    for (int fm = 0; fm < FM; ++fm) {
      const int m0 = bm + wm * (FM * 16) + fm * 16 + lg * 4;
      #pragma unroll
      for (int fn = 0; fn < FN; ++fn) {
        const int n = bn + wn * (BN / 2) + fn * 16 + lr;
        const float bs = b2f(bias[n]);
        #pragma unroll
        for (int r = 0; r < 4; ++r) {
          float v = acc[fm][fn][r] + bs;
          if (EPI == 1) v = 0.5f * v * (1.0f + erff(v * 0.70710678118654752f));
          if (EPI == 2) v += b2f(res[(size_t)(m0 + r) * N + n]);
          C[(size_t)(m0 + r) * N + n] = f2b(v);
        }
      }
    }
  }
}

// ====== fused per-bt transformer phase 1: qkv -> attention -> attnout+res+LN1 ======
__global__ __launch_bounds__(256, 1) void k_fat1(
    bf16* __restrict__ hbuf,
    const bf16* __restrict__ Wqkv, const bf16* __restrict__ Bqkv,
    const bf16* __restrict__ Wo, const bf16* __restrict__ Bo,
    const bf16* __restrict__ lw, const bf16* __restrict__ lb)
{
  __shared__ alignas(16) bf16 hs[32 * 256];
  __shared__ alignas(16) bf16 ao[32 * 256];
  __shared__ alignas(16) bf16 astage[128 * 64];
  __shared__ bf16 att[3 * 9216];
  __shared__ float ps[32][33];
  __shared__ float rs[32];
  __shared__ float psum[32][4], psq[32][4];
  __shared__ float mstat[32], istat[32];

  const int bt = blockIdx.x;
  const int tid = threadIdx.x;
  const int l = tid & 63, w = tid >> 6;
  const int lg = l >> 4, lr = l & 15;
  const int sr8 = l >> 3;
  const int sch = (l & 7) ^ sr8;
  char* hsb = (char*)hs;
  char* aob = (char*)ao;
  char* asb = (char*)astage;

  #pragma unroll
  for (int call = 0; call < 4; ++call) {
    const int id = call * 256 + tid;
    const int s = id >> 5, within = id & 31;
    const int grp = within >> 3, c = within & 7;
    gld16(hbuf + (size_t)(s * 256 + bt) * 256 + grp * 64 + ((c ^ (s & 7)) * 8),
          hsb + call * 4096 + w * 1024);
  }

  for (int at = 0; at < 6; ++at) {
    f32x4 acc[2][2];
    #pragma unroll
    for (int fm = 0; fm < 2; ++fm)
      #pragma unroll
      for (int fn = 0; fn < 2; ++fn) acc[fm][fn] = (f32x4){0.f, 0.f, 0.f, 0.f};
    for (int kst = 0; kst < 4; ++kst) {
      __syncthreads();
      #pragma unroll
      for (int it = 0; it < 4; ++it) {
        const int r = w * 8 + it * 32 + sr8;
        gld16(Wqkv + (size_t)(at * 128 + r) * 256 + kst * 64 + sch * 8,
              asb + w * 1024 + it * 4096);
      }
      __syncthreads();
      #pragma unroll
      for (int ks = 0; ks < 2; ++ks) {
        short8 af[2], bfr[2];
        #pragma unroll
        for (int fm = 0; fm < 2; ++fm) {
          const int r = w * 32 + fm * 16 + lr;
          af[fm] = *reinterpret_cast<const short8*>(asb + r * 128 + (((lg + ks * 4) ^ (r & 7)) * 16));
        }
        #pragma unroll
        for (int fn = 0; fn < 2; ++fn) {
          const int sr = fn * 16 + lr;
          bfr[fn] = *reinterpret_cast<const short8*>(hsb + sr * 512 + kst * 128 + (((lg + ks * 4) ^ (sr & 7)) * 16));
        }
        #pragma unroll
        for (int fm = 0; fm < 2; ++fm)
          #pragma unroll
          for (int fn = 0; fn < 2; ++fn)
            acc[fm][fn] = __builtin_amdgcn_mfma_f32_16x16x32_bf16(af[fm], bfr[fn], acc[fm][fn], 0, 0, 0);
      }
    }
    #pragma unroll
    for (int fm = 0; fm < 2; ++fm) {
      #pragma unroll
      for (int fn = 0; fn < 2; ++fn) {
        const int s = fn * 16 + lr;
        #pragma unroll
        for (int r = 0; r < 4; ++r) {
          const int n = at * 128 + w * 32 + fm * 16 + lg * 4 + r;
          const int p = n >> 8, rem = n & 255;
          att[p * 9216 + (rem >> 5) * 1152 + s * 36 + (rem & 31)] =
              f2b(acc[fm][fn][r] + b2f(Bqkv[n]));
        }
      }
    }
  }
  __syncthreads();

  const int s_a = tid >> 3, j_a = tid & 7;
  for (int hd = 0; hd < 8; ++hd) {
    const bf16* qrow = att + hd * 1152 + s_a * 36;
    float sc[4];
    #pragma unroll
    for (int e = 0; e < 4; ++e) {
      const int t = j_a + 8 * e;
      const bf16* krow = att + 9216 + hd * 1152 + t * 36;
      float v = 0.f;
      #pragma unroll
      for (int dd = 0; dd < 32; ++dd) v += b2f(qrow[dd]) * b2f(krow[dd]);
      sc[e] = v * 0.17677669529663687f;
    }
    float mx = fmaxf(fmaxf(sc[0], sc[1]), fmaxf(sc[2], sc[3]));
    #pragma unroll
    for (int mk = 1; mk < 8; mk <<= 1) mx = fmaxf(mx, __shfl_xor(mx, mk, 64));
    float sm = 0.f; float ex[4];
    #pragma unroll
    for (int e = 0; e < 4; ++e) { ex[e] = expf(sc[e] - mx); sm += ex[e]; }
    #pragma unroll
    for (int mk = 1; mk < 8; mk <<= 1) sm += __shfl_xor(sm, mk, 64);
    #pragma unroll
    for (int e = 0; e < 4; ++e) ps[s_a][j_a + 8 * e] = ex[e];
    if (j_a == 0) rs[s_a] = 1.0f / sm;
    __syncthreads();
    const float rinv = rs[s_a];
    float av[4];
    #pragma unroll
    for (int e = 0; e < 4; ++e) {
      const int dd = j_a * 4 + e;
      float a = 0.f;
      #pragma unroll
      for (int t = 0; t < 32; ++t)
        a += ps[s_a][t] * b2f(att[2 * 9216 + hd * 1152 + t * 36 + dd]);
      av[e] = a * rinv;
    }
    alignas(8) bf16 ov[4];
    #pragma unroll
    for (int e = 0; e < 4; ++e) ov[e] = f2b(av[e]);
    const int clog = (hd & 1) * 4 + (j_a >> 1);
    *reinterpret_cast<ushort4*>(aob + s_a * 512 + (hd >> 1) * 128 +
        ((clog ^ (s_a & 7)) * 16) + (j_a & 1) * 8) =
        *reinterpret_cast<const ushort4*>(ov);
    __syncthreads();
  }

  float vals[2][2][2][4];
  for (int at = 0; at < 2; ++at) {
    f32x4 acc[2][2];
    #pragma unroll
    for (int fm = 0; fm < 2; ++fm)
      #pragma unroll
      for (int fn = 0; fn < 2; ++fn) acc[fm][fn] = (f32x4){0.f, 0.f, 0.f, 0.f};
    for (int kst = 0; kst < 4; ++kst) {
      __syncthreads();
      #pragma unroll
      for (int it = 0; it < 4; ++it) {
        const int r = w * 8 + it * 32 + sr8;
        gld16(Wo + (size_t)(at * 128 + r) * 256 + kst * 64 + sch * 8,
              asb + w * 1024 + it * 4096);
      }
      __syncthreads();
      #pragma unroll
      for (int ks = 0; ks < 2; ++ks) {
        short8 af[2], bfr[2];
        #pragma unroll
        for (int fm = 0; fm < 2; ++fm) {
          const int r = w * 32 + fm * 16 + lr;
          af[fm] = *reinterpret_cast<const short8*>(asb + r * 128 + (((lg + ks * 4) ^ (r & 7)) * 16));
        }
        #pragma unroll
        for (int fn = 0; fn < 2; ++fn) {
          const int sr = fn * 16 + lr;
          bfr[fn] = *reinterpret_cast<const short8*>(aob + sr * 512 + kst * 128 + (((lg + ks * 4) ^ (sr & 7)) * 16));
        }
        #pragma unroll
        for (int fm = 0; fm < 2; ++fm)
          #pragma unroll
          for (int fn = 0; fn < 2; ++fn)
            acc[fm][fn] = __builtin_amdgcn_mfma_f32_16x16x32_bf16(af[fm], bfr[fn], acc[fm][fn], 0, 0, 0);
      }
    }
    #pragma unroll
    for (int fm = 0; fm < 2; ++fm)
      #pragma unroll
      for (int fn = 0; fn < 2; ++fn)
        #pragma unroll
        for (int r = 0; r < 4; ++r) vals[at][fm][fn][r] = acc[fm][fn][r];
  }

  float s1[2] = {0.f, 0.f}, s2[2] = {0.f, 0.f};
  #pragma unroll
  for (int at = 0; at < 2; ++at) {
    #pragma unroll
    for (int fm = 0; fm < 2; ++fm) {
      const int n4 = at * 128 + w * 32 + fm * 16 + lg * 4;
      #pragma unroll
      for (int fn = 0; fn < 2; ++fn) {
        const int s = fn * 16 + lr;
        const ushort4 hr = *reinterpret_cast<const ushort4*>(
            hsb + s * 512 + (n4 >> 6) * 128 + ((((n4 >> 3) & 7) ^ (s & 7)) * 16) + (n4 & 7) * 2);
        const bf16* hb = reinterpret_cast<const bf16*>(&hr);
        #pragma unroll
        for (int r = 0; r < 4; ++r) {
          const float v = vals[at][fm][fn][r] + b2f(Bo[n4 + r]) + b2f(hb[r]);
          vals[at][fm][fn][r] = v;
          s1[fn] += v;
          s2[fn] += v * v;
        }
      }
    }
  }
  #pragma unroll
  for (int fn = 0; fn < 2; ++fn) {
    float a = s1[fn], b = s2[fn];
    a += __shfl_xor(a, 16, 64); a += __shfl_xor(a, 32, 64);
    b += __shfl_xor(b, 16, 64); b += __shfl_xor(b, 32, 64);
    if (lg == 0) { psum[fn * 16 + lr][w] = a; psq[fn * 16 + lr][w] = b; }
  }
  __syncthreads();
  if (tid < 32) {
    float sa = 0.f, sb = 0.f;
    #pragma unroll
    for (int k = 0; k < 4; ++k) { sa += psum[tid][k]; sb += psq[tid][k]; }
    const float m = sa * (1.0f / 256.0f);
    mstat[tid] = m;
    istat[tid] = 1.0f / sqrtf(sb * (1.0f / 256.0f) - m * m + 1e-5f);
  }
  __syncthreads();
  #pragma unroll
  for (int at = 0; at < 2; ++at) {
    #pragma unroll
    for (int fm = 0; fm < 2; ++fm) {
      const int n4 = at * 128 + w * 32 + fm * 16 + lg * 4;
      #pragma unroll
      for (int fn = 0; fn < 2; ++fn) {
        const int s = fn * 16 + lr;
        const float m = mstat[s], inv = istat[s];
        alignas(8) bf16 ov[4];
        #pragma unroll
        for (int r = 0; r < 4; ++r)
          ov[r] = f2b((vals[at][fm][fn][r] - m) * inv * b2f(lw[n4 + r]) + b2f(lb[n4 + r]));
        *reinterpret_cast<ushort4*>(hbuf + (size_t)(s * 256 + bt) * 256 + n4) =
            *reinterpret_cast<const ushort4*>(ov);
      }
    }
  }
}

// ---- split-K reduce (bf16 partials) + bias (+res) + LN (+optional 2nd LN) ----
// wave-shfl (sum, sumsq) reduce + 4-word LDS combine
template<bool DOLN>
__global__ __launch_bounds__(256) void k_lnred(
    const bf16* __restrict__ Pf, const bf16* __restrict__ bias,
    const bf16* res, const bf16* __restrict__ lw, const bf16* __restrict__ lb,
    const bf16* lw2, const bf16* lb2,
    bf16* h, int kc)
{
  __shared__ float wsum[4], wsq[4];
  const int row = blockIdx.x, d = threadIdx.x;
  const int w = d >> 6;
  float s = 0.f;
  for (int z = 0; z < kc; ++z) s += b2f(Pf[((size_t)z * 8192 + row) * 256 + d]);
  s += b2f(bias[d]);
  if (res) s += b2f(res[(size_t)row * 256 + d]);
  if (!DOLN) { h[(size_t)row * 256 + d] = f2b(s); return; }
  float a = s, b = s * s;
  #pragma unroll
  for (int mk = 1; mk < 64; mk <<= 1) {
    a += __shfl_xor(a, mk, 64);
    b += __shfl_xor(b, mk, 64);
  }
  if ((d & 63) == 0) { wsum[w] = a; wsq[w] = b; }
  __syncthreads();
  float sa = wsum[0] + wsum[1] + wsum[2] + wsum[3];
  float sb = wsq[0] + wsq[1] + wsq[2] + wsq[3];
  float m = sa * (1.0f / 256.0f);
  float inv = 1.0f / sqrtf(sb * (1.0f / 256.0f) - m * m + 1e-5f);
  float y = (s - m) * inv * b2f(lw[d]) + b2f(lb[d]);
  if (lw2) {
    // fused second LayerNorm (lnf)
    __syncthreads();
    a = y; b = y * y;
    #pragma unroll
    for (int mk = 1; mk < 64; mk <<= 1) {
      a += __shfl_xor(a, mk, 64);
      b += __shfl_xor(b, mk, 64);
    }
    if ((d & 63) == 0) { wsum[w] = a; wsq[w] = b; }
    __syncthreads();
    sa = wsum[0] + wsum[1] + wsum[2] + wsum[3];
    sb = wsq[0] + wsq[1] + wsq[2] + wsq[3];
    m = sa * (1.0f / 256.0f);
    inv = 1.0f / sqrtf(sb * (1.0f / 256.0f) - m * m + 1e-5f);
    y = (y - m) * inv * b2f(lw2[d]) + b2f(lb2[d]);
  }
  h[(size_t)row * 256 + d] = f2b(y);
}

// ---- VQ merge over u64 keys (deterministic) ----
__global__ __launch_bounds__(256) void k_vqmerge(
    const u64* __restrict__ ku, int* __restrict__ idx, int M, int NB)
{
  const int r = blockIdx.x * 256 + threadIdx.x;
  if (r >= M) return;
  u64 best = ku[r];
  for (int nb = 1; nb < NB; ++nb) {
    const u64 k = ku[(size_t)nb * M + r];
    best = k < best ? k : best;
  }
  idx[r] = (int)(best & 0xFFFFFFFFull);
}

// ---- codebook norms ----
__global__ __launch_bounds__(256) void k_cnorm(const bf16* __restrict__ cb, float* __restrict__ cn)
{
  const int j = blockIdx.x * 256 + threadIdx.x;
  const u32* p = (const u32*)(cb + (size_t)j * 256);
  float s = 0.f;
  for (int k = 0; k < 128; ++k) {
    const u32 v = p[k];
    const float a = plo(v), b = phi(v);
    s += a * a + b * b;
  }
  cn[j] = s;
}

// ---- gather codebook -> padded channels-last a0 + per-row loss partials ----
__global__ __launch_bounds__(256) void k_gather(
    const bf16* h, const bf16* cb, const int* idx, bf16* a0, float* lsum)
{
  __shared__ float ws[4];
  const int row = blockIdx.x, d = threadIdx.x;
  const int w = d >> 6;
  const int code = idx[row] & 8191;
  const float q = b2f(cb[(size_t)code * 256 + d]);
  const float x = b2f(h[(size_t)row * 256 + d]);
  float v = (q - x) * (q - x);
  #pragma unroll
  for (int mk = 1; mk < 64; mk <<= 1) v += __shfl_xor(v, mk, 64);
  if ((d & 63) == 0) ws[w] = v;
  __syncthreads();
  if (d == 0) lsum[row] = ws[0] + ws[1] + ws[2] + ws[3];
  const int b = row >> 8, n = row & 255;
  const int y = n >> 4, xc = n & 15;
  a0[(((size_t)b * 18 + y + 1) * 18 + (xc + 1)) * 256 + d] = f2b(q);
}

// ---- deterministic loss reduce -> f32 scalar ----
__global__ __launch_bounds__(256) void k_loss(const float* lsum, float* out)
{
  __shared__ float red[256];
  const int tid = threadIdx.x;
  float v = 0.f;
  for (int i = 0; i < 32; ++i) v += lsum[tid + 256 * i];
  red[tid] = v;
  __syncthreads();
  for (int off = 128; off > 0; off >>= 1) {
    if (tid < off) red[tid] += red[tid + off];
    __syncthreads();
  }
  if (tid == 0)
    out[0] = red[0] * (1.25f / 2097152.0f);
}

// ---- decoder weight transform ----
__global__ __launch_bounds__(256) void k_wtrans(
    const bf16* __restrict__ w, bf16* __restrict__ wt,
    int Cin, int lCin, int CoutR, int CoutP)
{
  const int K = Cin << 2;
  const int total = 4 * CoutP * K;
  const int i = blockIdx.x * 256 + threadIdx.x;
  if (i >= total) return;
  const int p = i / (CoutP * K);
  const int rem = i - p * (CoutP * K);
  const int co = rem / K;
  const int k = rem - co * K;
  const int tap = k >> lCin, ci = k - (tap << lCin);
  const int py = p >> 1, px = p & 1, ty = tap >> 1, tx = tap & 1;
  bf16 v = f2b(0.f);
  if (co < CoutR)
    v = w[(((size_t)ci * CoutR + co) * 4 + py + 2 * ty) * 4 + px + 2 * tx];
  wt[i] = v;
}

// ====== decoder convT implicit MFMA GEMM, double-buffered 2-phase ======
__global__ __launch_bounds__(256, 2) void convt64(
    const bf16* __restrict__ in, const bf16* __restrict__ Wt,
    const bf16* __restrict__ bias, bf16* __restrict__ outp,
    int H, int lH, int Cin, int lCin, int Cout)
{
  __shared__ alignas(16) bf16 As[2][128 * 64];
  __shared__ alignas(16) bf16 Bs[2][64 * 64];
  const int tid = threadIdx.x;
  const int pz = blockIdx.z;
  const int py = pz >> 1, px = pz & 1;
  const int K = Cin << 2;
  const int bn = blockIdx.x * 64, bm = blockIdx.y * 128;
  const bf16* Bw = Wt + (size_t)pz * Cout * K;
  const int l = tid & 63, w = tid >> 6;
  const int wm = w >> 1, wn = w & 1;
  const int lg = l >> 4, lr = l & 15;
  const int sr8 = l >> 3;
  const int sch = (l & 7) ^ sr8;
  const int Hp = H + 2;
  f32x4 acc[4][2];
  #pragma unroll
  for (int fm = 0; fm < 4; ++fm)
    #pragma unroll
    for (int fn = 0; fn < 2; ++fn) acc[fm][fn] = (f32x4){0.f, 0.f, 0.f, 0.f};

  size_t pixbase[4];
  #pragma unroll
  for (int it = 0; it < 4; ++it) {
    const int m = bm + w * 8 + it * 32 + sr8;
    const int b = m >> (2 * lH);
    const int rem = m & ((1 << (2 * lH)) - 1);
    const int jj = rem >> lH, ii = rem & (H - 1);
    pixbase[it] = ((size_t)(b * Hp + jj) * Hp + ii);
  }

  auto stage = [&](int bb, int k0) {
    char* ab = (char*)As[bb];
    char* bp = (char*)Bs[bb];
    const int tap = k0 >> lCin;
    const int ty = tap >> 1, tx = tap & 1;
    const int sy = (1 - py) + (1 - ty);
    const int sx = (1 - px) + (1 - tx);
    const int ci0 = (k0 - (tap << lCin)) + sch * 8;
    #pragma unroll
    for (int it = 0; it < 4; ++it)
      gld16(in + (pixbase[it] + (size_t)sy * Hp + sx) * Cin + ci0,
            ab + w * 1024 + it * 4096);
    #pragma unroll
    for (int it = 0; it < 2; ++it) {
      const int r = w * 8 + it * 32 + sr8;
      gld16(Bw + (size_t)(bn + r) * K + k0 + sch * 8, bp + w * 1024 + it * 4096);
    }
  };

  const int nt = K >> 6;
  stage(0, 0);
  __syncthreads();
  for (int t = 0; t < nt; ++t) {
    const int cur = t & 1;
    if (t + 1 < nt) stage(cur ^ 1, (t + 1) << 6);
    const char* ab = (const char*)As[cur];
    const char* bb = (const char*)Bs[cur];
    #pragma unroll
    for (int ks = 0; ks < 2; ++ks) {
      short8 af[4], bfr[2];
      #pragma unroll
      for (int fm = 0; fm < 4; ++fm) {
        const int r = wm * 64 + fm * 16 + lr;
        af[fm] = *reinterpret_cast<const short8*>(ab + r * 128 + (((lg + ks * 4) ^ (r & 7)) * 16));
      }
      #pragma unroll
      for (int fn = 0; fn < 2; ++fn) {
        const int r = wn * 32 + fn * 16 + lr;
        bfr[fn] = *reinterpret_cast<const short8*>(bb + r * 128 + (((lg + ks * 4) ^ (r & 7)) * 16));
      }
      #pragma unroll
      for (int fm = 0; fm < 4; ++fm)
        #pragma unroll
        for (int fn = 0; fn < 2; ++fn)
          acc[fm][fn] = __builtin_amdgcn_mfma_f32_16x16x32_bf16(af[fm], bfr[fn], acc[fm][fn], 0, 0, 0);
    }
    __syncthreads();
  }

  const int Ho = 2 * H, Hop = Ho + 2;
  #pragma unroll
  for (int fm = 0; fm < 4; ++fm) {
    const int m0 = bm + wm * 64 + fm * 16 + lg * 4;
    #pragma unroll
    for (int fn = 0; fn < 2; ++fn) {
      const int n = bn + wn * 32 + fn * 16 + lr;
      #pragma unroll
      for (int r = 0; r < 4; ++r) {
        const int m = m0 + r;
        const int b = m >> (2 * lH);
        const int rem = m & ((1 << (2 * lH)) - 1);
        const int jj = rem >> lH, ii = rem & (H - 1);
        const int oy = 2 * jj + (1 - py), ox = 2 * ii + (1 - px);
        const float v = fmaxf(acc[fm][fn][r] + b2f(bias[n]), 0.f);
        outp[((size_t)(b * Hop + oy + 1) * Hop + ox + 1) * Cout + n] = f2b(v);
      }
    }
  }
}

// ---- final decoder layer (Cout=3): coalesced vector kernel ----
__global__ __launch_bounds__(256) void k_dec3(
    const bf16* __restrict__ a3, const bf16* __restrict__ wt3,
    const bf16* __restrict__ bias, float* __restrict__ xhat, int chunkBase)
{
  __shared__ float wl[3][264];
  const int tid = threadIdx.x;
  const int pz = blockIdx.y;
  const int py = pz >> 1, px = pz & 1;
  for (int i = tid; i < 768; i += 256) {
    const int co = i >> 8, k = i & 255;
    wl[co][k] = b2f(wt3[(pz * 3 + co) * 256 + k]);
  }
  __syncthreads();
  const int b = blockIdx.z;
  const int p = blockIdx.x * 64 + (tid >> 2);
  const int jj = p >> 7, ii = p & 127;
  const int ch4 = tid & 3;
  float a0 = 0.f, a1 = 0.f, a2 = 0.f;
  #pragma unroll
  for (int ty = 0; ty < 2; ++ty) {
    #pragma unroll
    for (int tx = 0; tx < 2; ++tx) {
      const int sy = (1 - py) + (1 - ty), sx = (1 - px) + (1 - tx);
      const int tap = ty * 2 + tx;
      const u32* ip = (const u32*)(a3 + ((size_t)(b * 130 + jj + sy) * 130 + ii + sx) * 64) + ch4 * 8;
      const float* w0 = &wl[0][tap * 64 + ch4 * 16];
      const float* w1 = &wl[1][tap * 64 + ch4 * 16];
      const float* w2 = &wl[2][tap * 64 + ch4 * 16];
      #pragma unroll
      for (int kk = 0; kk < 8; ++kk) {
        const u32 v = ip[kk];
        const float e0 = plo(v), e1 = phi(v);
        a0 += e0 * w0[2 * kk] + e1 * w0[2 * kk + 1];
        a1 += e0 * w1[2 * kk] + e1 * w1[2 * kk + 1];
        a2 += e0 * w2[2 * kk] + e1 * w2[2 * kk + 1];
      }
    }
  }
  a0 += __shfl_xor(a0, 1, 64); a0 += __shfl_xor(a0, 2, 64);
  a1 += __shfl_xor(a1, 1, 64); a1 += __shfl_xor(a1, 2, 64);
  a2 += __shfl_xor(a2, 1, 64); a2 += __shfl_xor(a2, 2, 64);
  if (ch4 < 3) {
    const float av = ch4 == 0 ? a0 : (ch4 == 1 ? a1 : a2);
    const int oy = 2 * jj + (1 - py), ox = 2 * ii + (1 - px);
    const float t = av + b2f(bias[ch4]);
    xhat[(((size_t)(chunkBase + b) * 3 + ch4) * 256 + oy) * 256 + ox] =
        1.0f / (1.0f + expf(-t));
  }
}

// =====================================================================
extern "C" void kernel_launch(void* const* d_in, const int* in_sizes, int n_in,
                              void* d_out, int out_size, void* d_ws, size_t ws_size,
                              hipStream_t stream)
{
  float* xhat = (float*)d_out;
  float* lossout = xhat + (out_size - 1);

  const size_t NEED = 130195456;
  if (ws_size < NEED) return;

  char* ws = (char*)d_ws;
  int*   flag  = (int*)  (ws + 0);
  float* lsum  = (float*)(ws + 1024);
  int*   idx   = (int*)  (ws + 65536);
  u64*   ku    = (u64*)  (ws + 131072);
  bf16*  P     = (bf16*) (ws + 8519680);
  bf16*  WT    = (bf16*) (ws + 27262976);
  float* cnorm = (float*)(ws + 30900224);
  bf16*  hbuf  = (bf16*) (ws + 31457280);
  bf16*  A_im  = (bf16*) (ws + 35651584);
  bf16*  ffb   = (bf16*) (ws + 52428800);
  bf16*  Pfb   = (bf16*) (ws + 85983232);
  bf16*  a0    = (bf16*) (ws + 35651584);
  bf16*  a1    = (bf16*) (ws + 40960000);
  bf16*  a2    = (bf16*) (ws + 59899904);
  bf16*  a3    = (bf16*) (ws + 95584256);

  k_detect<<<1, 64, 0, stream>>>((const u32*)d_in[7], flag);

  size_t poff[26]; poff[1] = 0;
  for (int i = 2; i <= 25; ++i) poff[i] = poff[i - 1] + (size_t)in_sizes[i - 1];
  const size_t ptotal = poff[25] + (size_t)in_sizes[25];
  PPack pp;
  for (int i = 0; i < 25; ++i) { pp.s[i] = d_in[i + 1]; pp.off[i] = (u32)poff[i + 1]; }
  pp.off[25] = (u32)ptotal;
  k_convall<<<(int)((ptotal + 255) / 256), 256, 0, stream>>>(pp, P, flag);

  const bf16 *patch_w = P + poff[1],  *patch_b = P + poff[2];
  const bf16 *qkv_w   = P + poff[3],  *qkv_b   = P + poff[4];
  const bf16 *out_w   = P + poff[5],  *out_b   = P + poff[6];
  const bf16 *ln1_w   = P + poff[7],  *ln1_b   = P + poff[8];
  const bf16 *ln2_w   = P + poff[9],  *ln2_b   = P + poff[10];
  const bf16 *ff1_w   = P + poff[11], *ff1_b   = P + poff[12];
  const bf16 *ff2_w   = P + poff[13], *ff2_b   = P + poff[14];
  const bf16 *lnf_w   = P + poff[15], *lnf_b   = P + poff[16];
  const bf16 *codebook= P + poff[17];
  const bf16 *dec_w0  = P + poff[18], *dec_b0  = P + poff[19];
  const bf16 *dec_w1  = P + poff[20], *dec_b1  = P + poff[21];
  const bf16 *dec_w2  = P + poff[22], *dec_b2  = P + poff[23];
  const bf16 *dec_w3  = P + poff[24], *dec_b3  = P + poff[25];

  bf16* wt0 = WT;
  bf16* wt1 = wt0 + 1048576;
  bf16* wt2 = wt1 + 524288;
  bf16* wt3 = wt2 + 131072;
  k_wtrans<<<(1048576 + 255) / 256, 256, 0, stream>>>(dec_w0, wt0, 256, 8, 256, 256);
  k_wtrans<<<(524288 + 255) / 256, 256, 0, stream>>>(dec_w1, wt1, 256, 8, 128, 128);
  k_wtrans<<<(131072 + 255) / 256, 256, 0, stream>>>(dec_w2, wt2, 128, 7, 64, 64);
  k_wtrans<<<(3072 + 255) / 256, 256, 0, stream>>>(dec_w3, wt3, 64, 6, 3, 3);
  k_cnorm<<<32, 256, 0, stream>>>(codebook, cnorm);

  // patch embedding: split-K (4 x Kc=768, dbuf) -> bf16 partials + reduce+bias
  k_im2col<<<dim3(3, 8192), 128, 0, stream>>>(d_in[0], A_im, flag);
  gemm_t<4, 2, 128, true><<<dim3(2, 128, 4), 256, 0, stream>>>(
      A_im, patch_w, nullptr, nullptr, Pfb, nullptr, nullptr, 8192, 256, 3072, 768);
  k_lnred<false><<<8192, 256, 0, stream>>>(
      Pfb, patch_b, nullptr, nullptr, nullptr, nullptr, nullptr, hbuf, 4);

  // transformer encoder: fused attention block + FF path (ff2 split-K depth 2);
  // layer 5's lnred additionally applies lnf
  for (int l = 0; l < 6; ++l) {
    k_fat1<<<256, 256, 0, stream>>>(
        hbuf, qkv_w + (size_t)l * 768 * 256, qkv_b + l * 768,
        out_w + (size_t)l * 256 * 256, out_b + l * 256,
        ln1_w + l * 256, ln1_b + l * 256);
    gemm_t<1, 2, 256, false><<<dim3(4, 128, 1), 256, 0, stream>>>(
        hbuf, ff1_w + (size_t)l * 1024 * 256, ff1_b + l * 1024, nullptr, ffb,
        nullptr, nullptr, 8192, 1024, 256, 256);
    gemm_t<4, 2, 128, false><<<dim3(2, 128, 2), 256, 0, stream>>>(
        ffb, ff2_w + (size_t)l * 256 * 1024, nullptr, nullptr, Pfb,
        nullptr, nullptr, 8192, 256, 1024, 512);
    k_lnred<true><<<8192, 256, 0, stream>>>(
        Pfb, ff2_b + l * 256, hbuf, ln2_w + l * 256, ln2_b + l * 256,
        (l == 5) ? lnf_w : nullptr, (l == 5) ? lnf_b : nullptr, hbuf, 2);
  }

  // VQ via MFMA + packed-key argmin (proven FM=2 x BN=256 config)
  gemm_t<3, 2, 256, false><<<dim3(32, 128, 1), 256, 0, stream>>>(
      hbuf, codebook, nullptr, nullptr, nullptr, cnorm, ku, 8192, 8192, 256, 256);
  k_vqmerge<<<32, 256, 0, stream>>>(ku, idx, 8192, 32);

  k_zborder<<<(32 * 68 * 32 + 255) / 256, 256, 0, stream>>>(a0, 18, 256, 32);
  k_gather<<<8192, 256, 0, stream>>>(hbuf, codebook, idx, a0, lsum);
  k_loss<<<1, 256, 0, stream>>>(lsum, lossout);
  k_zborder<<<(32 * 132 * 32 + 255) / 256, 256, 0, stream>>>(a1, 34, 256, 32);
  k_zborder<<<(32 * 260 * 16 + 255) / 256, 256, 0, stream>>>(a2, 66, 128, 32);
  k_zborder<<<(16 * 516 * 8 + 255) / 256, 256, 0, stream>>>(a3, 130, 64, 16);

  // decoder
  convt64<<<dim3(4, 64, 4), 256, 0, stream>>>(a0, wt0, dec_b0, a1, 16, 4, 256, 8, 256);
  convt64<<<dim3(2, 256, 4), 256, 0, stream>>>(a1, wt1, dec_b1, a2, 32, 5, 256, 8, 128);
  for (int c = 0; c < 2; ++c) {
    const bf16* a2c = a2 + (size_t)c * 16 * 66 * 66 * 128;
    convt64<<<dim3(1, 512, 4), 256, 0, stream>>>(a2c, wt2, dec_b2, a3, 64, 6, 128, 7, 64);
    k_dec3<<<dim3(256, 4, 16), 256, 0, stream>>>(a3, wt3, dec_b3, xhat, c * 16);
  }
}